// Round 1
// baseline (1992.766 us; speedup 1.0000x reference)
//
#include <hip/hip_runtime.h>

#define HW 28
#define NPIX 784   // 28*28
#define NIMG 64

// ---------------------------------------------------------------------------
// Kernel 1: grid distance-sort constants.
// For each pixel i: stable argsort of squared distances to all pixels.
// d2 values are exact small integers (<=1458); stable order = sort by (d2, j).
// Rank via O(N^2) counting. Output u16 sort index + u16 d2 (exact).
// ---------------------------------------------------------------------------
__global__ void build_consts_kernel(unsigned short* __restrict__ sortIdx,
                                    unsigned short* __restrict__ d2s) {
    __shared__ int d2[NPIX];
    int i = blockIdx.x;
    int ii = i / HW, ij = i % HW;
    for (int j = threadIdx.x; j < NPIX; j += blockDim.x) {
        int di = ii - j / HW;
        int dj = ij - j % HW;
        d2[j] = di * di + dj * dj;
    }
    __syncthreads();
    for (int j = threadIdx.x; j < NPIX; j += blockDim.x) {
        int dj2 = d2[j];
        int rank = 0;
        for (int q = 0; q < NPIX; ++q) {
            int dq = d2[q];
            rank += (dq < dj2) || (dq == dj2 && q < j);
        }
        sortIdx[i * NPIX + rank] = (unsigned short)j;
        d2s[i * NPIX + rank] = (unsigned short)dj2;
    }
}

// ---------------------------------------------------------------------------
// Kernel 2: per-image sums (for the DTM mass bound).
// ---------------------------------------------------------------------------
__global__ void row_sum_kernel(const float* __restrict__ x, float* __restrict__ sums) {
    int m = blockIdx.x;
    float acc = 0.f;
    for (int j = threadIdx.x; j < NPIX; j += blockDim.x) acc += x[m * NPIX + j];
    for (int off = 32; off > 0; off >>= 1) acc += __shfl_down(acc, off, 64);
    __shared__ float red[4];
    int lane = threadIdx.x & 63, w = threadIdx.x >> 6;
    if (lane == 0) red[w] = acc;
    __syncthreads();
    if (threadIdx.x == 0) sums[m] = red[0] + red[1] + red[2] + red[3];
}

// ---------------------------------------------------------------------------
// Kernel 3: DTM. One wave per (m, i). Wave-level inclusive scan over the
// distance-sorted weights; both m0 bounds (0.05, 0.2) in one pass.
// eff = clamp(bound - exclusive_cum, 0, w);  f = sqrt(sum(eff*d2)/bound)
// ---------------------------------------------------------------------------
__global__ void dtm_kernel(const float* __restrict__ x,
                           const unsigned short* __restrict__ sortIdx,
                           const unsigned short* __restrict__ d2s,
                           const float* __restrict__ sums,
                           float* __restrict__ F) {
    int wid = blockIdx.x * 4 + (threadIdx.x >> 6);
    int lane = threadIdx.x & 63;
    int m = wid / NPIX;
    int i = wid % NPIX;
    if (m >= NIMG) return;
    float s = sums[m];
    float bound1 = 0.05f * s, bound2 = 0.2f * s;
    const float* xr = x + m * NPIX;
    const unsigned short* si = sortIdx + (size_t)i * NPIX;
    const unsigned short* dr = d2s + (size_t)i * NPIX;
    float carry = 0.f, acc1 = 0.f, acc2 = 0.f;
    for (int c = 0; c < NPIX; c += 64) {
        int j = c + lane;
        float w = 0.f, d2 = 0.f;
        if (j < NPIX) {
            w = xr[si[j]];
            d2 = (float)(int)dr[j];
        }
        float v = w;
        for (int off = 1; off < 64; off <<= 1) {
            float t = __shfl_up(v, off, 64);
            if (lane >= off) v += t;
        }
        float cumex = carry + v - w;  // exclusive prefix
        float e1 = fminf(fmaxf(bound1 - cumex, 0.f), w);
        float e2 = fminf(fmaxf(bound2 - cumex, 0.f), w);
        acc1 += e1 * d2;
        acc2 += e2 * d2;
        carry += __shfl(v, 63, 64);
    }
    for (int off = 32; off > 0; off >>= 1) {
        acc1 += __shfl_down(acc1, off, 64);
        acc2 += __shfl_down(acc2, off, 64);
    }
    if (lane == 0) {
        F[0 * NIMG * NPIX + m * NPIX + i] = sqrtf(acc1 / bound1);
        F[1 * NIMG * NPIX + m * NPIX + i] = sqrtf(acc2 / bound2);
    }
}

// ---------------------------------------------------------------------------
// Kernel 4: stable ranks. task = feat*128 + dir*64 + m.
// dir 0: ascending f (sublevel); dir 1: descending f (== ascending -f).
// Ties broken by index ascending (matches np.argsort stable in both cases).
// ---------------------------------------------------------------------------
__global__ void rank_kernel(const float* __restrict__ F,
                            int* __restrict__ POS, int* __restrict__ ORD) {
    __shared__ float fv[NPIX];
    int task = blockIdx.x;
    int feat = task >> 7;
    int dir = (task >> 6) & 1;
    int m = task & 63;
    const float* fr = F + feat * NIMG * NPIX + m * NPIX;
    for (int j = threadIdx.x; j < NPIX; j += blockDim.x) fv[j] = fr[j];
    __syncthreads();
    int* pos = POS + task * NPIX;
    int* ord = ORD + task * NPIX;
    for (int i = threadIdx.x; i < NPIX; i += blockDim.x) {
        float fi = fv[i];
        int rank = 0;
        if (dir == 0) {
            for (int q = 0; q < NPIX; ++q) {
                float fq = fv[q];
                rank += (fq < fi) || (fq == fi && q < i);
            }
        } else {
            for (int q = 0; q < NPIX; ++q) {
                float fq = fv[q];
                rank += (fq > fi) || (fq == fi && q < i);
            }
        }
        pos[i] = rank;
        ord[rank] = i;
    }
}

// ---------------------------------------------------------------------------
// Kernel 5: union-find persistence pairs. One wave per task (4 tasks/block).
// Key invariant (from the reference: birth[] is never written): the UF root
// IS the birth vertex, so only parent[] + read-only pos[] are needed.
// dir 0: 4-connectivity on ascending order, pair (dying_root, v).
// dir 1: 8-connectivity on descending order, pair stored swapped (v, dying_root).
// 63 lanes do parallel init; lane 0 runs the serial sweep with path-halving.
// ---------------------------------------------------------------------------
__global__ void __launch_bounds__(256) uf_kernel(const int* __restrict__ POS,
                                                 const int* __restrict__ ORD,
                                                 int* __restrict__ BI, int* __restrict__ DI) {
    __shared__ int sh[4 * 3 * NPIX];  // per wave: parent, pos, ord
    int wave = threadIdx.x >> 6;
    int lane = threadIdx.x & 63;
    int task = blockIdx.x * 4 + wave;
    int feat = task >> 7;
    int dir = (task >> 6) & 1;
    int m = task & 63;
    int* par = sh + wave * 3 * NPIX;
    int* bp = par + NPIX;   // bp[s] == pos[s] forever; roots: birth pos
    int* ord = bp + NPIX;
    const int* gpos = POS + task * NPIX;
    const int* gord = ORD + task * NPIX;
    for (int s = lane; s < NPIX; s += 64) {
        par[s] = s;
        bp[s] = gpos[s];
        ord[s] = gord[s];
    }
    __syncthreads();
    if (lane == 0) {
        int base = ((feat * NIMG + m) * 2 + dir) * NPIX;
        int* bi = BI + base;
        int* di = DI + base;
        int k = 0;
        const int nn = dir ? 8 : 4;
        const int dxs[8] = {-1, 1, 0, 0, -1, -1, 1, 1};
        const int dys[8] = {0, 0, -1, 1, -1, 1, -1, 1};
        for (int r = 1; r < NPIX; ++r) {
            int v = ord[r];
            int vi = v / HW, vj = v % HW;
            int rv = v;
            for (;;) { int p = par[rv]; if (p == rv) break; int g = par[p]; par[rv] = g; rv = g; }
            for (int o = 0; o < nn; ++o) {
                int ui = vi + dxs[o], uj = vj + dys[o];
                if (ui < 0 || ui >= HW || uj < 0 || uj >= HW) continue;
                int u = ui * HW + uj;
                if (bp[u] >= r) continue;  // neighbor not yet added
                int ru = u;
                for (;;) { int p = par[ru]; if (p == ru) break; int g = par[p]; par[ru] = g; ru = g; }
                if (ru == rv) continue;
                int lb;
                if (bp[ru] <= bp[rv]) { lb = rv; par[rv] = ru; rv = ru; }
                else                  { lb = ru; par[ru] = rv; }
                if (dir == 0) { bi[k] = lb; di[k] = v; }
                else          { bi[k] = v;  di[k] = lb; }
                ++k;
            }
        }
        for (; k < NPIX; ++k) { bi[k] = 0; di[k] = 0; }  // zero-pad (matches ref)
    }
}

// ---------------------------------------------------------------------------
// Kernel 6: persistence landscape. block = feat*128 + m*2 + h.
// tent(t) = clamp(min(t - b, d - t), 0); top-K over 784 pairs per t (K<=3).
// Feature layout: h*(K*T) + k*T + t.
// ---------------------------------------------------------------------------
__global__ void landscape_kernel(const float* __restrict__ F,
                                 const int* __restrict__ BI, const int* __restrict__ DI,
                                 float* __restrict__ LAM1, float* __restrict__ LAM2) {
    __shared__ float bb[NPIX], dd[NPIX];
    int blk = blockIdx.x;
    int feat = blk >> 7;
    int m = (blk >> 1) & 63;
    int h = blk & 1;
    const float* fr = F + feat * NIMG * NPIX + m * NPIX;
    int base = ((feat * NIMG + m) * 2 + h) * NPIX;
    for (int p = threadIdx.x; p < NPIX; p += blockDim.x) {
        bb[p] = fr[BI[base + p]];
        dd[p] = fr[DI[base + p]];
    }
    __syncthreads();
    if (threadIdx.x < 32) {
        int t = threadIdx.x;
        int K = (feat == 0) ? 2 : 3;
        float start = (feat == 0) ? 0.f : 1.f;
        float end = (feat == 0) ? 7.f : 8.f;
        float tv = start + (end - start) * ((float)t / 31.f);
        float v0 = 0.f, v1 = 0.f, v2 = 0.f;
        for (int p = 0; p < NPIX; ++p) {
            float tent = fmaxf(fminf(tv - bb[p], dd[p] - tv), 0.f);
            if (tent > v0)      { v2 = v1; v1 = v0; v0 = tent; }
            else if (tent > v1) { v2 = v1; v1 = tent; }
            else if (tent > v2) { v2 = tent; }
        }
        if (feat == 0) {
            float* lam = LAM1 + m * 128 + h * 64;
            lam[0 * 32 + t] = v0;
            lam[1 * 32 + t] = v1;
        } else {
            float* lam = LAM2 + m * 192 + h * 96;
            lam[0 * 32 + t] = v0;
            lam[1 * 32 + t] = v1;
            lam[2 * 32 + t] = v2;
        }
    }
}

// ---------------------------------------------------------------------------
// Kernel 7: MLP head. One block (64 threads) per image.
// ---------------------------------------------------------------------------
__global__ void mlp_kernel(const float* __restrict__ LAM1, const float* __restrict__ LAM2,
                           const float* __restrict__ w1, const float* __restrict__ b1,
                           const float* __restrict__ w2, const float* __restrict__ b2,
                           const float* __restrict__ wf, const float* __restrict__ bf,
                           float* __restrict__ out) {
    __shared__ float xc[64];
    int m = blockIdx.x;
    int n = threadIdx.x;
    if (n < 32) {
        float acc = b1[n];
        const float* l = LAM1 + m * 128;
        for (int c = 0; c < 128; ++c) acc += w1[n * 128 + c] * l[c];
        xc[n] = fmaxf(acc, 0.f);
    } else {
        int n2 = n - 32;
        float acc = b2[n2];
        const float* l = LAM2 + m * 192;
        for (int c = 0; c < 192; ++c) acc += w2[n2 * 192 + c] * l[c];
        xc[n] = fmaxf(acc, 0.f);
    }
    __syncthreads();
    if (n < 10) {
        float acc = bf[n];
        for (int c = 0; c < 64; ++c) acc += wf[n * 64 + c] * xc[c];
        out[m * 10 + n] = acc;
    }
}

extern "C" void kernel_launch(void* const* d_in, const int* in_sizes, int n_in,
                              void* d_out, int out_size, void* d_ws, size_t ws_size,
                              hipStream_t stream) {
    const float* x  = (const float*)d_in[0];
    const float* w1 = (const float*)d_in[1];
    const float* b1 = (const float*)d_in[2];
    const float* w2 = (const float*)d_in[3];
    const float* b2 = (const float*)d_in[4];
    const float* wf = (const float*)d_in[5];
    const float* bf = (const float*)d_in[6];
    float* out = (float*)d_out;

    char* ws = (char*)d_ws;
    size_t off = 0;
    unsigned short* SORT = (unsigned short*)(ws + off); off += (size_t)NPIX * NPIX * 2;  // 1.23 MB
    unsigned short* D2S  = (unsigned short*)(ws + off); off += (size_t)NPIX * NPIX * 2;  // 1.23 MB
    float* SUMS = (float*)(ws + off); off += 256;
    float* F    = (float*)(ws + off); off += (size_t)2 * NIMG * NPIX * 4;   // f1, f2
    int* POS    = (int*)(ws + off);   off += (size_t)256 * NPIX * 4;
    int* ORD    = (int*)(ws + off);   off += (size_t)256 * NPIX * 4;
    int* BI     = (int*)(ws + off);   off += (size_t)256 * NPIX * 4;
    int* DI     = (int*)(ws + off);   off += (size_t)256 * NPIX * 4;
    float* LAM1 = (float*)(ws + off); off += (size_t)NIMG * 128 * 4;
    float* LAM2 = (float*)(ws + off); off += (size_t)NIMG * 192 * 4;

    build_consts_kernel<<<NPIX, 256, 0, stream>>>(SORT, D2S);
    row_sum_kernel<<<NIMG, 256, 0, stream>>>(x, SUMS);
    dtm_kernel<<<(NIMG * NPIX) / 4, 256, 0, stream>>>(x, SORT, D2S, SUMS, F);
    rank_kernel<<<256, 256, 0, stream>>>(F, POS, ORD);
    uf_kernel<<<64, 256, 0, stream>>>(POS, ORD, BI, DI);
    landscape_kernel<<<256, 256, 0, stream>>>(F, BI, DI, LAM1, LAM2);
    mlp_kernel<<<NIMG, 64, 0, stream>>>(LAM1, LAM2, w1, b1, w2, b2, wf, bf, out);
}

// Round 2
// 1010.362 us; speedup vs baseline: 1.9723x; 1.9723x over previous
//
#include <hip/hip_runtime.h>

#define HW 28
#define NPIX 784   // 28*28
#define NIMG 64

// ---------------------------------------------------------------------------
// Kernel 1: grid distance-sort constants.
// For each pixel i: stable argsort of squared distances to all pixels.
// d2 values are exact small integers (<=1458); stable order = sort by (d2, j).
// Rank via O(N^2) counting. Output u16 sort index + u16 d2 (exact).
// ---------------------------------------------------------------------------
__global__ void build_consts_kernel(unsigned short* __restrict__ sortIdx,
                                    unsigned short* __restrict__ d2s) {
    __shared__ int d2[NPIX];
    int i = blockIdx.x;
    int ii = i / HW, ij = i % HW;
    for (int j = threadIdx.x; j < NPIX; j += blockDim.x) {
        int di = ii - j / HW;
        int dj = ij - j % HW;
        d2[j] = di * di + dj * dj;
    }
    __syncthreads();
    for (int j = threadIdx.x; j < NPIX; j += blockDim.x) {
        int dj2 = d2[j];
        int rank = 0;
        for (int q = 0; q < NPIX; ++q) {
            int dq = d2[q];
            rank += (dq < dj2) || (dq == dj2 && q < j);
        }
        sortIdx[i * NPIX + rank] = (unsigned short)j;
        d2s[i * NPIX + rank] = (unsigned short)dj2;
    }
}

// ---------------------------------------------------------------------------
// Kernel 2: per-image sums (for the DTM mass bound).
// ---------------------------------------------------------------------------
__global__ void row_sum_kernel(const float* __restrict__ x, float* __restrict__ sums) {
    int m = blockIdx.x;
    float acc = 0.f;
    for (int j = threadIdx.x; j < NPIX; j += blockDim.x) acc += x[m * NPIX + j];
    for (int off = 32; off > 0; off >>= 1) acc += __shfl_down(acc, off, 64);
    __shared__ float red[4];
    int lane = threadIdx.x & 63, w = threadIdx.x >> 6;
    if (lane == 0) red[w] = acc;
    __syncthreads();
    if (threadIdx.x == 0) sums[m] = red[0] + red[1] + red[2] + red[3];
}

// ---------------------------------------------------------------------------
// Kernel 3: DTM. One wave per (m, i). Wave-level inclusive scan over the
// distance-sorted weights; both m0 bounds (0.05, 0.2) in one pass.
// ---------------------------------------------------------------------------
__global__ void dtm_kernel(const float* __restrict__ x,
                           const unsigned short* __restrict__ sortIdx,
                           const unsigned short* __restrict__ d2s,
                           const float* __restrict__ sums,
                           float* __restrict__ F) {
    int wid = blockIdx.x * 4 + (threadIdx.x >> 6);
    int lane = threadIdx.x & 63;
    int m = wid / NPIX;
    int i = wid % NPIX;
    if (m >= NIMG) return;
    float s = sums[m];
    float bound1 = 0.05f * s, bound2 = 0.2f * s;
    const float* xr = x + m * NPIX;
    const unsigned short* si = sortIdx + (size_t)i * NPIX;
    const unsigned short* dr = d2s + (size_t)i * NPIX;
    float carry = 0.f, acc1 = 0.f, acc2 = 0.f;
    for (int c = 0; c < NPIX; c += 64) {
        int j = c + lane;
        float w = 0.f, d2 = 0.f;
        if (j < NPIX) {
            w = xr[si[j]];
            d2 = (float)(int)dr[j];
        }
        float v = w;
        for (int off = 1; off < 64; off <<= 1) {
            float t = __shfl_up(v, off, 64);
            if (lane >= off) v += t;
        }
        float cumex = carry + v - w;  // exclusive prefix
        float e1 = fminf(fmaxf(bound1 - cumex, 0.f), w);
        float e2 = fminf(fmaxf(bound2 - cumex, 0.f), w);
        acc1 += e1 * d2;
        acc2 += e2 * d2;
        carry += __shfl(v, 63, 64);
    }
    for (int off = 32; off > 0; off >>= 1) {
        acc1 += __shfl_down(acc1, off, 64);
        acc2 += __shfl_down(acc2, off, 64);
    }
    if (lane == 0) {
        F[0 * NIMG * NPIX + m * NPIX + i] = sqrtf(acc1 / bound1);
        F[1 * NIMG * NPIX + m * NPIX + i] = sqrtf(acc2 / bound2);
    }
}

// ---------------------------------------------------------------------------
// Kernel 4: stable ranks. task = feat*128 + dir*64 + m.
// dir 0: ascending f; dir 1: descending f. Ties by index ascending.
// ---------------------------------------------------------------------------
__global__ void rank_kernel(const float* __restrict__ F,
                            int* __restrict__ POS, int* __restrict__ ORD) {
    __shared__ float fv[NPIX];
    int task = blockIdx.x;
    int feat = task >> 7;
    int dir = (task >> 6) & 1;
    int m = task & 63;
    const float* fr = F + feat * NIMG * NPIX + m * NPIX;
    for (int j = threadIdx.x; j < NPIX; j += blockDim.x) fv[j] = fr[j];
    __syncthreads();
    int* pos = POS + task * NPIX;
    int* ord = ORD + task * NPIX;
    for (int i = threadIdx.x; i < NPIX; i += blockDim.x) {
        float fi = fv[i];
        int rank = 0;
        if (dir == 0) {
            for (int q = 0; q < NPIX; ++q) {
                float fq = fv[q];
                rank += (fq < fi) || (fq == fi && q < i);
            }
        } else {
            for (int q = 0; q < NPIX; ++q) {
                float fq = fv[q];
                rank += (fq > fi) || (fq == fi && q < i);
            }
        }
        pos[i] = rank;
        ord[rank] = i;
    }
}

// ---------------------------------------------------------------------------
// Kernel 5: union-find persistence pairs — wave-parallel merge step.
// One wave (= one block of 64) per task. Per vertex v (rank order):
//   lanes 0..7 find the roots of the (added) neighbors IN PARALLEL;
//   lane 8 represents v's fresh root; dedupe + min-birth winner via
//   shuffles; every non-winner root emits pair (root, v) and links
//   DIRECTLY to the winner (flatter than the reference's halving).
// Pair-set equals the reference's pair-set (order-invariant elder rule;
// the reference's zero-persistence (v,v) first-merge pair contributes 0
// to every tent, identical to the zero padding).
// pb[s] = {parent, pos}: one ds_read_b64 gives the "added?" check and the
// first find step together. pos never changes.
// ---------------------------------------------------------------------------
__global__ void __launch_bounds__(64) uf_kernel(const int* __restrict__ POS,
                                                const int* __restrict__ ORD,
                                                int* __restrict__ BI, int* __restrict__ DI) {
    __shared__ int2 pb[NPIX];
    __shared__ int ordA[NPIX];
    int lane = threadIdx.x;
    int task = blockIdx.x;
    int feat = task >> 7;
    int dir = (task >> 6) & 1;
    int m = task & 63;
    const int* gpos = POS + task * NPIX;
    const int* gord = ORD + task * NPIX;
    for (int s = lane; s < NPIX; s += 64) {
        pb[s] = make_int2(s, gpos[s]);
        ordA[s] = gord[s];
    }
    __syncthreads();

    int base = ((feat * NIMG + m) * 2 + dir) * NPIX;
    int* bi = BI + base;
    int* di = DI + base;
    int k = 0;
    const int nn = dir ? 8 : 4;
    // packed dx/dy (+1, 2 bits each) for offsets {-1,0},{1,0},{0,-1},{0,1},
    // {-1,-1},{-1,1},{1,-1},{1,1}
    const unsigned DXP = 41048u;  // 0,2,1,1,0,0,2,2
    const unsigned DYP = 34949u;  // 1,1,0,2,0,2,0,2
    int dx = ((DXP >> (2 * (lane & 7))) & 3) - 1;
    int dy = ((DYP >> (2 * (lane & 7))) & 3) - 1;

    int vcur = ordA[1];
    for (int r = 1; r < NPIX; ++r) {
        int vnext = ordA[(r + 1 < NPIX) ? (r + 1) : 0];  // prefetch (hidden latency)
        int v = vcur;
        int vi = v / HW, vj = v % HW;

        int root = -1, rootbp = 0x7fffffff;
        if (lane < nn) {
            int ui = vi + dx, uj = vj + dy;
            if ((unsigned)ui < HW && (unsigned)uj < HW) {
                int x = ui * HW + uj;
                int2 e = pb[x];
                if (e.y < r) {  // neighbor already added
                    while (e.x != x) {
                        int p = e.x;
                        int2 ep = pb[p];
                        if (ep.x != p) pb[x].x = ep.x;  // grandparent shortcut
                        x = p; e = ep;
                    }
                    root = x; rootbp = e.y;
                }
            }
        }
        unsigned long long nbrMask = __ballot(root >= 0);
        if (nbrMask != 0ull) {
            if (lane == 8) { root = v; rootbp = r; }  // v's fresh root
            // dedupe: keep first occurrence among lanes 0..7 (lane 8 always uniq)
            bool uniq = (root >= 0);
            #pragma unroll
            for (int o = 0; o < 8; ++o) {
                int ro = __shfl(root, o, 64);
                if (lane > o && ro >= 0 && ro == root) uniq = false;
            }
            // min-by-birth-pos over uniq roots (lanes 0..8 live in group of 16)
            int bk = (uniq && root >= 0) ? rootbp : 0x7fffffff;
            int br = root;
            #pragma unroll
            for (int off = 1; off < 16; off <<= 1) {
                int ok = __shfl_xor(bk, off, 64);
                int orr = __shfl_xor(br, off, 64);
                if (ok < bk) { bk = ok; br = orr; }
            }
            int winner = __shfl(br, 0, 64);
            bool emit = uniq && root >= 0 && root != winner;
            unsigned long long em = __ballot(emit);
            if (emit) {
                int slot = k + (int)__popcll(em & ((1ull << lane) - 1ull));
                if (dir == 0) { bi[slot] = root; di[slot] = v; }
                else          { bi[slot] = v;    di[slot] = root; }
                pb[root].x = winner;  // link loser directly to winner
            }
            k += (int)__popcll(em);
        }
        vcur = vnext;
    }
    // zero-pad unused slots (matches reference zeros; (0,0) tents are 0)
    for (int s = k + lane; s < NPIX; s += 64) { bi[s] = 0; di[s] = 0; }
}

// ---------------------------------------------------------------------------
// Kernel 6: persistence landscape. block = feat*128 + m*2 + h.
// ---------------------------------------------------------------------------
__global__ void landscape_kernel(const float* __restrict__ F,
                                 const int* __restrict__ BI, const int* __restrict__ DI,
                                 float* __restrict__ LAM1, float* __restrict__ LAM2) {
    __shared__ float bb[NPIX], dd[NPIX];
    int blk = blockIdx.x;
    int feat = blk >> 7;
    int m = (blk >> 1) & 63;
    int h = blk & 1;
    const float* fr = F + feat * NIMG * NPIX + m * NPIX;
    int base = ((feat * NIMG + m) * 2 + h) * NPIX;
    for (int p = threadIdx.x; p < NPIX; p += blockDim.x) {
        bb[p] = fr[BI[base + p]];
        dd[p] = fr[DI[base + p]];
    }
    __syncthreads();
    if (threadIdx.x < 32) {
        int t = threadIdx.x;
        float start = (feat == 0) ? 0.f : 1.f;
        float end = (feat == 0) ? 7.f : 8.f;
        float tv = start + (end - start) * ((float)t / 31.f);
        float v0 = 0.f, v1 = 0.f, v2 = 0.f;
        for (int p = 0; p < NPIX; ++p) {
            float tent = fmaxf(fminf(tv - bb[p], dd[p] - tv), 0.f);
            if (tent > v0)      { v2 = v1; v1 = v0; v0 = tent; }
            else if (tent > v1) { v2 = v1; v1 = tent; }
            else if (tent > v2) { v2 = tent; }
        }
        if (feat == 0) {
            float* lam = LAM1 + m * 128 + h * 64;
            lam[0 * 32 + t] = v0;
            lam[1 * 32 + t] = v1;
        } else {
            float* lam = LAM2 + m * 192 + h * 96;
            lam[0 * 32 + t] = v0;
            lam[1 * 32 + t] = v1;
            lam[2 * 32 + t] = v2;
        }
    }
}

// ---------------------------------------------------------------------------
// Kernel 7: MLP head. One block (64 threads) per image.
// ---------------------------------------------------------------------------
__global__ void mlp_kernel(const float* __restrict__ LAM1, const float* __restrict__ LAM2,
                           const float* __restrict__ w1, const float* __restrict__ b1,
                           const float* __restrict__ w2, const float* __restrict__ b2,
                           const float* __restrict__ wf, const float* __restrict__ bf,
                           float* __restrict__ out) {
    __shared__ float xc[64];
    int m = blockIdx.x;
    int n = threadIdx.x;
    if (n < 32) {
        float acc = b1[n];
        const float* l = LAM1 + m * 128;
        for (int c = 0; c < 128; ++c) acc += w1[n * 128 + c] * l[c];
        xc[n] = fmaxf(acc, 0.f);
    } else {
        int n2 = n - 32;
        float acc = b2[n2];
        const float* l = LAM2 + m * 192;
        for (int c = 0; c < 192; ++c) acc += w2[n2 * 192 + c] * l[c];
        xc[n] = fmaxf(acc, 0.f);
    }
    __syncthreads();
    if (n < 10) {
        float acc = bf[n];
        for (int c = 0; c < 64; ++c) acc += wf[n * 64 + c] * xc[c];
        out[m * 10 + n] = acc;
    }
}

extern "C" void kernel_launch(void* const* d_in, const int* in_sizes, int n_in,
                              void* d_out, int out_size, void* d_ws, size_t ws_size,
                              hipStream_t stream) {
    const float* x  = (const float*)d_in[0];
    const float* w1 = (const float*)d_in[1];
    const float* b1 = (const float*)d_in[2];
    const float* w2 = (const float*)d_in[3];
    const float* b2 = (const float*)d_in[4];
    const float* wf = (const float*)d_in[5];
    const float* bf = (const float*)d_in[6];
    float* out = (float*)d_out;

    char* ws = (char*)d_ws;
    size_t off = 0;
    unsigned short* SORT = (unsigned short*)(ws + off); off += (size_t)NPIX * NPIX * 2;
    unsigned short* D2S  = (unsigned short*)(ws + off); off += (size_t)NPIX * NPIX * 2;
    float* SUMS = (float*)(ws + off); off += 256;
    float* F    = (float*)(ws + off); off += (size_t)2 * NIMG * NPIX * 4;
    int* POS    = (int*)(ws + off);   off += (size_t)256 * NPIX * 4;
    int* ORD    = (int*)(ws + off);   off += (size_t)256 * NPIX * 4;
    int* BI     = (int*)(ws + off);   off += (size_t)256 * NPIX * 4;
    int* DI     = (int*)(ws + off);   off += (size_t)256 * NPIX * 4;
    float* LAM1 = (float*)(ws + off); off += (size_t)NIMG * 128 * 4;
    float* LAM2 = (float*)(ws + off); off += (size_t)NIMG * 192 * 4;

    build_consts_kernel<<<NPIX, 256, 0, stream>>>(SORT, D2S);
    row_sum_kernel<<<NIMG, 256, 0, stream>>>(x, SUMS);
    dtm_kernel<<<(NIMG * NPIX) / 4, 256, 0, stream>>>(x, SORT, D2S, SUMS, F);
    rank_kernel<<<256, 256, 0, stream>>>(F, POS, ORD);
    uf_kernel<<<256, 64, 0, stream>>>(POS, ORD, BI, DI);
    landscape_kernel<<<256, 256, 0, stream>>>(F, BI, DI, LAM1, LAM2);
    mlp_kernel<<<NIMG, 64, 0, stream>>>(LAM1, LAM2, w1, b1, w2, b2, wf, bf, out);
}

// Round 3
// 768.217 us; speedup vs baseline: 2.5940x; 1.3152x over previous
//
#include <hip/hip_runtime.h>

#define HW 28
#define NPIX 784   // 28*28
#define NIMG 64

// ---------------------------------------------------------------------------
// Kernel 1: grid distance-sort constants.
// ---------------------------------------------------------------------------
__global__ void build_consts_kernel(unsigned short* __restrict__ sortIdx,
                                    unsigned short* __restrict__ d2s) {
    __shared__ int d2[NPIX];
    int i = blockIdx.x;
    int ii = i / HW, ij = i % HW;
    for (int j = threadIdx.x; j < NPIX; j += blockDim.x) {
        int di = ii - j / HW;
        int dj = ij - j % HW;
        d2[j] = di * di + dj * dj;
    }
    __syncthreads();
    for (int j = threadIdx.x; j < NPIX; j += blockDim.x) {
        int dj2 = d2[j];
        int rank = 0;
        for (int q = 0; q < NPIX; ++q) {
            int dq = d2[q];
            rank += (dq < dj2) || (dq == dj2 && q < j);
        }
        sortIdx[i * NPIX + rank] = (unsigned short)j;
        d2s[i * NPIX + rank] = (unsigned short)dj2;
    }
}

// ---------------------------------------------------------------------------
// Kernel 2: per-image sums (for the DTM mass bound).
// ---------------------------------------------------------------------------
__global__ void row_sum_kernel(const float* __restrict__ x, float* __restrict__ sums) {
    int m = blockIdx.x;
    float acc = 0.f;
    for (int j = threadIdx.x; j < NPIX; j += blockDim.x) acc += x[m * NPIX + j];
    for (int off = 32; off > 0; off >>= 1) acc += __shfl_down(acc, off, 64);
    __shared__ float red[4];
    int lane = threadIdx.x & 63, w = threadIdx.x >> 6;
    if (lane == 0) red[w] = acc;
    __syncthreads();
    if (threadIdx.x == 0) sums[m] = red[0] + red[1] + red[2] + red[3];
}

// ---------------------------------------------------------------------------
// Kernel 3: DTM. One wave per (m, i).
// ---------------------------------------------------------------------------
__global__ void dtm_kernel(const float* __restrict__ x,
                           const unsigned short* __restrict__ sortIdx,
                           const unsigned short* __restrict__ d2s,
                           const float* __restrict__ sums,
                           float* __restrict__ F) {
    int wid = blockIdx.x * 4 + (threadIdx.x >> 6);
    int lane = threadIdx.x & 63;
    int m = wid / NPIX;
    int i = wid % NPIX;
    if (m >= NIMG) return;
    float s = sums[m];
    float bound1 = 0.05f * s, bound2 = 0.2f * s;
    const float* xr = x + m * NPIX;
    const unsigned short* si = sortIdx + (size_t)i * NPIX;
    const unsigned short* dr = d2s + (size_t)i * NPIX;
    float carry = 0.f, acc1 = 0.f, acc2 = 0.f;
    for (int c = 0; c < NPIX; c += 64) {
        int j = c + lane;
        float w = 0.f, d2 = 0.f;
        if (j < NPIX) {
            w = xr[si[j]];
            d2 = (float)(int)dr[j];
        }
        float v = w;
        for (int off = 1; off < 64; off <<= 1) {
            float t = __shfl_up(v, off, 64);
            if (lane >= off) v += t;
        }
        float cumex = carry + v - w;  // exclusive prefix
        float e1 = fminf(fmaxf(bound1 - cumex, 0.f), w);
        float e2 = fminf(fmaxf(bound2 - cumex, 0.f), w);
        acc1 += e1 * d2;
        acc2 += e2 * d2;
        carry += __shfl(v, 63, 64);
    }
    for (int off = 32; off > 0; off >>= 1) {
        acc1 += __shfl_down(acc1, off, 64);
        acc2 += __shfl_down(acc2, off, 64);
    }
    if (lane == 0) {
        F[0 * NIMG * NPIX + m * NPIX + i] = sqrtf(acc1 / bound1);
        F[1 * NIMG * NPIX + m * NPIX + i] = sqrtf(acc2 / bound2);
    }
}

// ---------------------------------------------------------------------------
// Kernel 4: stable ranks. task = feat*128 + dir*64 + m.
// ---------------------------------------------------------------------------
__global__ void rank_kernel(const float* __restrict__ F,
                            int* __restrict__ POS, int* __restrict__ ORD) {
    __shared__ float fv[NPIX];
    int task = blockIdx.x;
    int feat = task >> 7;
    int dir = (task >> 6) & 1;
    int m = task & 63;
    const float* fr = F + feat * NIMG * NPIX + m * NPIX;
    for (int j = threadIdx.x; j < NPIX; j += blockDim.x) fv[j] = fr[j];
    __syncthreads();
    int* pos = POS + task * NPIX;
    int* ord = ORD + task * NPIX;
    for (int i = threadIdx.x; i < NPIX; i += blockDim.x) {
        float fi = fv[i];
        int rank = 0;
        if (dir == 0) {
            for (int q = 0; q < NPIX; ++q) {
                float fq = fv[q];
                rank += (fq < fi) || (fq == fi && q < i);
            }
        } else {
            for (int q = 0; q < NPIX; ++q) {
                float fq = fv[q];
                rank += (fq > fi) || (fq == fi && q < i);
            }
        }
        pos[i] = rank;
        ord[rank] = i;
    }
}

// ---------------------------------------------------------------------------
// Kernel 5: union-find persistence pairs — wave-parallel find, SALU reduce.
// One wave per task. Per vertex v (rank order):
//   lanes 0..nn-1 find roots of added neighbors in parallel (LDS);
//   ALL cross-lane reduction via v_readlane (SALU) — no DS-pipe shuffles:
//     winner = min over packed keys (bp<<10|root), wave-uniform in SGPR;
//   losers emit (root, v) and link directly to the winner; v links too.
// The reference's zero-persistence (v,v) first-merge pair contributes 0 to
// every tent == the zero padding, so it is not emitted.
// ---------------------------------------------------------------------------
__global__ void __launch_bounds__(64) uf_kernel(const int* __restrict__ POS,
                                                const int* __restrict__ ORD,
                                                int* __restrict__ BI, int* __restrict__ DI) {
    __shared__ int2 pb[NPIX];   // {parent, pos}; pos never changes
    __shared__ int ordA[NPIX];
    int lane = threadIdx.x;
    int task = blockIdx.x;
    int feat = task >> 7;
    int dir = (task >> 6) & 1;
    int m = task & 63;
    const int* gpos = POS + task * NPIX;
    const int* gord = ORD + task * NPIX;
    for (int s = lane; s < NPIX; s += 64) {
        pb[s] = make_int2(s, gpos[s]);
        ordA[s] = gord[s];
    }
    __syncthreads();

    int base = ((feat * NIMG + m) * 2 + dir) * NPIX;
    int* bi = BI + base;
    int* di = DI + base;
    int k = 0;
    const int nn = dir ? 8 : 4;
    // packed dx/dy (+1, 2 bits each) for offsets {-1,0},{1,0},{0,-1},{0,1},
    // {-1,-1},{-1,1},{1,-1},{1,1}
    const unsigned DXP = 41048u;  // 0,2,1,1,0,0,2,2
    const unsigned DYP = 34949u;  // 1,1,0,2,0,2,0,2
    int dx = ((DXP >> (2 * (lane & 7))) & 3) - 1;
    int dy = ((DYP >> (2 * (lane & 7))) & 3) - 1;

    int vcur = ordA[1];
    for (int r = 1; r < NPIX; ++r) {
        int vnext = ordA[(r + 1 < NPIX) ? (r + 1) : 0];  // prefetch
        int v = vcur;
        int vi = v / HW, vj = v % HW;

        int root = -1, rootbp = 0;
        if (lane < nn) {
            int ui = vi + dx, uj = vj + dy;
            if ((unsigned)ui < HW && (unsigned)uj < HW) {
                int x = ui * HW + uj;
                int2 e = pb[x];
                if (e.y < r) {  // neighbor already added
                    while (e.x != x) {
                        int p = e.x;
                        int2 ep = pb[p];
                        if (ep.x != p) pb[x].x = ep.x;  // grandparent shortcut
                        x = p; e = ep;
                    }
                    root = x; rootbp = e.y;
                }
            }
        }
        // packed candidate key; SALU min across lanes 0..7 (+ v's own key)
        int key = (root >= 0) ? ((rootbp << 10) | root) : 0x7fffffff;
        int k0 = __builtin_amdgcn_readlane(key, 0);
        int k1 = __builtin_amdgcn_readlane(key, 1);
        int k2 = __builtin_amdgcn_readlane(key, 2);
        int k3 = __builtin_amdgcn_readlane(key, 3);
        int k4 = __builtin_amdgcn_readlane(key, 4);
        int k5 = __builtin_amdgcn_readlane(key, 5);
        int k6 = __builtin_amdgcn_readlane(key, 6);
        int k7 = __builtin_amdgcn_readlane(key, 7);
        int wkey = min(min(min(k0, k1), min(k2, k3)), min(min(k4, k5), min(k6, k7)));
        int ownkey = (r << 10) | v;           // v is always the youngest
        bool anyNbr = (wkey != 0x7fffffff);   // wkey < ownkey whenever a nbr exists
        int winner = (anyNbr ? wkey : ownkey) & 1023;  // uniform (SGPR)

        // dedupe via readlane (SALU): emit iff root unique among lower lanes
        bool emit = (root >= 0) && (root != winner);
        int r0 = __builtin_amdgcn_readlane(root, 0);
        int r1 = __builtin_amdgcn_readlane(root, 1);
        int r2 = __builtin_amdgcn_readlane(root, 2);
        int r3 = __builtin_amdgcn_readlane(root, 3);
        int r4 = __builtin_amdgcn_readlane(root, 4);
        int r5 = __builtin_amdgcn_readlane(root, 5);
        int r6 = __builtin_amdgcn_readlane(root, 6);
        if (lane > 0 && r0 == root) emit = false;
        if (lane > 1 && r1 == root) emit = false;
        if (lane > 2 && r2 == root) emit = false;
        if (lane > 3 && r3 == root) emit = false;
        if (lane > 4 && r4 == root) emit = false;
        if (lane > 5 && r5 == root) emit = false;
        if (lane > 6 && r6 == root) emit = false;

        unsigned long long em = __ballot(emit);
        if (emit) {
            int slot = k + (int)__popcll(em & ((1ull << lane) - 1ull));
            if (dir == 0) { bi[slot] = root; di[slot] = v; }
            else          { bi[slot] = v;    di[slot] = root; }
            pb[root].x = winner;  // link loser directly to winner
        }
        if (lane == 0 && anyNbr) pb[v].x = winner;  // v joins the winner
        k += (int)__popcll(em);
        vcur = vnext;
    }
    // zero-pad unused slots (matches reference zeros; (0,0) tents are 0)
    for (int s = k + lane; s < NPIX; s += 64) { bi[s] = 0; di[s] = 0; }
}

// ---------------------------------------------------------------------------
// Kernel 6: persistence landscape. block = feat*128 + m*2 + h.
// ---------------------------------------------------------------------------
__global__ void landscape_kernel(const float* __restrict__ F,
                                 const int* __restrict__ BI, const int* __restrict__ DI,
                                 float* __restrict__ LAM1, float* __restrict__ LAM2) {
    __shared__ float bb[NPIX], dd[NPIX];
    int blk = blockIdx.x;
    int feat = blk >> 7;
    int m = (blk >> 1) & 63;
    int h = blk & 1;
    const float* fr = F + feat * NIMG * NPIX + m * NPIX;
    int base = ((feat * NIMG + m) * 2 + h) * NPIX;
    for (int p = threadIdx.x; p < NPIX; p += blockDim.x) {
        bb[p] = fr[BI[base + p]];
        dd[p] = fr[DI[base + p]];
    }
    __syncthreads();
    if (threadIdx.x < 32) {
        int t = threadIdx.x;
        float start = (feat == 0) ? 0.f : 1.f;
        float end = (feat == 0) ? 7.f : 8.f;
        float tv = start + (end - start) * ((float)t / 31.f);
        float v0 = 0.f, v1 = 0.f, v2 = 0.f;
        for (int p = 0; p < NPIX; ++p) {
            float tent = fmaxf(fminf(tv - bb[p], dd[p] - tv), 0.f);
            if (tent > v0)      { v2 = v1; v1 = v0; v0 = tent; }
            else if (tent > v1) { v2 = v1; v1 = tent; }
            else if (tent > v2) { v2 = tent; }
        }
        if (feat == 0) {
            float* lam = LAM1 + m * 128 + h * 64;
            lam[0 * 32 + t] = v0;
            lam[1 * 32 + t] = v1;
        } else {
            float* lam = LAM2 + m * 192 + h * 96;
            lam[0 * 32 + t] = v0;
            lam[1 * 32 + t] = v1;
            lam[2 * 32 + t] = v2;
        }
    }
}

// ---------------------------------------------------------------------------
// Kernel 7: MLP head. One block (64 threads) per image.
// ---------------------------------------------------------------------------
__global__ void mlp_kernel(const float* __restrict__ LAM1, const float* __restrict__ LAM2,
                           const float* __restrict__ w1, const float* __restrict__ b1,
                           const float* __restrict__ w2, const float* __restrict__ b2,
                           const float* __restrict__ wf, const float* __restrict__ bf,
                           float* __restrict__ out) {
    __shared__ float xc[64];
    int m = blockIdx.x;
    int n = threadIdx.x;
    if (n < 32) {
        float acc = b1[n];
        const float* l = LAM1 + m * 128;
        for (int c = 0; c < 128; ++c) acc += w1[n * 128 + c] * l[c];
        xc[n] = fmaxf(acc, 0.f);
    } else {
        int n2 = n - 32;
        float acc = b2[n2];
        const float* l = LAM2 + m * 192;
        for (int c = 0; c < 192; ++c) acc += w2[n2 * 192 + c] * l[c];
        xc[n] = fmaxf(acc, 0.f);
    }
    __syncthreads();
    if (n < 10) {
        float acc = bf[n];
        for (int c = 0; c < 64; ++c) acc += wf[n * 64 + c] * xc[c];
        out[m * 10 + n] = acc;
    }
}

extern "C" void kernel_launch(void* const* d_in, const int* in_sizes, int n_in,
                              void* d_out, int out_size, void* d_ws, size_t ws_size,
                              hipStream_t stream) {
    const float* x  = (const float*)d_in[0];
    const float* w1 = (const float*)d_in[1];
    const float* b1 = (const float*)d_in[2];
    const float* w2 = (const float*)d_in[3];
    const float* b2 = (const float*)d_in[4];
    const float* wf = (const float*)d_in[5];
    const float* bf = (const float*)d_in[6];
    float* out = (float*)d_out;

    char* ws = (char*)d_ws;
    size_t off = 0;
    unsigned short* SORT = (unsigned short*)(ws + off); off += (size_t)NPIX * NPIX * 2;
    unsigned short* D2S  = (unsigned short*)(ws + off); off += (size_t)NPIX * NPIX * 2;
    float* SUMS = (float*)(ws + off); off += 256;
    float* F    = (float*)(ws + off); off += (size_t)2 * NIMG * NPIX * 4;
    int* POS    = (int*)(ws + off);   off += (size_t)256 * NPIX * 4;
    int* ORD    = (int*)(ws + off);   off += (size_t)256 * NPIX * 4;
    int* BI     = (int*)(ws + off);   off += (size_t)256 * NPIX * 4;
    int* DI     = (int*)(ws + off);   off += (size_t)256 * NPIX * 4;
    float* LAM1 = (float*)(ws + off); off += (size_t)NIMG * 128 * 4;
    float* LAM2 = (float*)(ws + off); off += (size_t)NIMG * 192 * 4;

    build_consts_kernel<<<NPIX, 256, 0, stream>>>(SORT, D2S);
    row_sum_kernel<<<NIMG, 256, 0, stream>>>(x, SUMS);
    dtm_kernel<<<(NIMG * NPIX) / 4, 256, 0, stream>>>(x, SORT, D2S, SUMS, F);
    rank_kernel<<<256, 256, 0, stream>>>(F, POS, ORD);
    uf_kernel<<<256, 64, 0, stream>>>(POS, ORD, BI, DI);
    landscape_kernel<<<256, 256, 0, stream>>>(F, BI, DI, LAM1, LAM2);
    mlp_kernel<<<NIMG, 64, 0, stream>>>(LAM1, LAM2, w1, b1, w2, b2, wf, bf, out);
}

// Round 4
// 694.972 us; speedup vs baseline: 2.8674x; 1.1054x over previous
//
#include <hip/hip_runtime.h>

#define HW 28
#define NPIX 784   // 28*28
#define NIMG 64

// ---------------------------------------------------------------------------
// Kernel 1: grid distance-sort constants.
// ---------------------------------------------------------------------------
__global__ void build_consts_kernel(unsigned short* __restrict__ sortIdx,
                                    unsigned short* __restrict__ d2s) {
    __shared__ int d2[NPIX];
    int i = blockIdx.x;
    int ii = i / HW, ij = i % HW;
    for (int j = threadIdx.x; j < NPIX; j += blockDim.x) {
        int di = ii - j / HW;
        int dj = ij - j % HW;
        d2[j] = di * di + dj * dj;
    }
    __syncthreads();
    for (int j = threadIdx.x; j < NPIX; j += blockDim.x) {
        int dj2 = d2[j];
        int rank = 0;
        for (int q = 0; q < NPIX; ++q) {
            int dq = d2[q];
            rank += (dq < dj2) || (dq == dj2 && q < j);
        }
        sortIdx[i * NPIX + rank] = (unsigned short)j;
        d2s[i * NPIX + rank] = (unsigned short)dj2;
    }
}

// ---------------------------------------------------------------------------
// Kernel 2: per-image sums (for the DTM mass bound).
// ---------------------------------------------------------------------------
__global__ void row_sum_kernel(const float* __restrict__ x, float* __restrict__ sums) {
    int m = blockIdx.x;
    float acc = 0.f;
    for (int j = threadIdx.x; j < NPIX; j += blockDim.x) acc += x[m * NPIX + j];
    for (int off = 32; off > 0; off >>= 1) acc += __shfl_down(acc, off, 64);
    __shared__ float red[4];
    int lane = threadIdx.x & 63, w = threadIdx.x >> 6;
    if (lane == 0) red[w] = acc;
    __syncthreads();
    if (threadIdx.x == 0) sums[m] = red[0] + red[1] + red[2] + red[3];
}

// ---------------------------------------------------------------------------
// Kernel 3: DTM. One wave per (m, i). 2 elements/lane (128/chunk) halves the
// DS-pipe scan traffic; ushort2 table loads.
// ---------------------------------------------------------------------------
__global__ void dtm_kernel(const float* __restrict__ x,
                           const unsigned short* __restrict__ sortIdx,
                           const unsigned short* __restrict__ d2s,
                           const float* __restrict__ sums,
                           float* __restrict__ F) {
    int wid = blockIdx.x * 4 + (threadIdx.x >> 6);
    int lane = threadIdx.x & 63;
    int m = wid / NPIX;
    int i = wid % NPIX;
    if (m >= NIMG) return;
    float s = sums[m];
    float bound1 = 0.05f * s, bound2 = 0.2f * s;
    const float* xr = x + m * NPIX;
    const unsigned short* si = sortIdx + (size_t)i * NPIX;
    const unsigned short* dr = d2s + (size_t)i * NPIX;
    float carry = 0.f, acc1 = 0.f, acc2 = 0.f;
    for (int c = 0; c < 7; ++c) {
        int j0 = c * 128 + lane * 2;
        float w0 = 0.f, w1 = 0.f, d0 = 0.f, d1 = 0.f;
        if (j0 < NPIX) {  // 784 even; j0 even, so j0+1 also in range
            ushort2 sv = *(const ushort2*)(si + j0);
            ushort2 dv = *(const ushort2*)(dr + j0);
            w0 = xr[sv.x]; w1 = xr[sv.y];
            d0 = (float)dv.x; d1 = (float)dv.y;
        }
        float ps = w0 + w1;
        float v = ps;
        for (int off = 1; off < 64; off <<= 1) {
            float t = __shfl_up(v, off, 64);
            if (lane >= off) v += t;
        }
        float cum0 = carry + v - ps;   // exclusive prefix before elem0
        float cum1 = cum0 + w0;
        acc1 += fminf(fmaxf(bound1 - cum0, 0.f), w0) * d0
              + fminf(fmaxf(bound1 - cum1, 0.f), w1) * d1;
        acc2 += fminf(fmaxf(bound2 - cum0, 0.f), w0) * d0
              + fminf(fmaxf(bound2 - cum1, 0.f), w1) * d1;
        carry += __shfl(v, 63, 64);
    }
    for (int off = 32; off > 0; off >>= 1) {
        acc1 += __shfl_down(acc1, off, 64);
        acc2 += __shfl_down(acc2, off, 64);
    }
    if (lane == 0) {
        F[0 * NIMG * NPIX + m * NPIX + i] = sqrtf(acc1 / bound1);
        F[1 * NIMG * NPIX + m * NPIX + i] = sqrtf(acc2 / bound2);
    }
}

// ---------------------------------------------------------------------------
// Kernel 4: stable ranks. task = feat*128 + dir*64 + m.
// ---------------------------------------------------------------------------
__global__ void rank_kernel(const float* __restrict__ F,
                            int* __restrict__ POS, int* __restrict__ ORD) {
    __shared__ float fv[NPIX];
    int task = blockIdx.x;
    int feat = task >> 7;
    int dir = (task >> 6) & 1;
    int m = task & 63;
    const float* fr = F + feat * NIMG * NPIX + m * NPIX;
    for (int j = threadIdx.x; j < NPIX; j += blockDim.x) fv[j] = fr[j];
    __syncthreads();
    int* pos = POS + task * NPIX;
    int* ord = ORD + task * NPIX;
    for (int i = threadIdx.x; i < NPIX; i += blockDim.x) {
        float fi = fv[i];
        int rank = 0;
        if (dir == 0) {
            for (int q = 0; q < NPIX; ++q) {
                float fq = fv[q];
                rank += (fq < fi) || (fq == fi && q < i);
            }
        } else {
            for (int q = 0; q < NPIX; ++q) {
                float fq = fv[q];
                rank += (fq > fi) || (fq == fi && q < i);
            }
        }
        pos[i] = rank;
        ord[rank] = i;
    }
}

// ---------------------------------------------------------------------------
// Kernel 5: union-find — BATCHED speculative merges, 7 vertices per wave-step.
// Group j = lanes 9j..9j+8: 8 neighbor-find slots + 1 self slot.
// Phase A (parallel): all lanes find their neighbor's root vs batch-start
//   state (lock-free path compression: links only move toward ancestors).
// Phase B (serial over j=0..6, all in registers):
//   keys k0..k8 via v_readlane; winner = SALU min of packed (bp<<10|root);
//   dedupe+emit via VALU compares + ballot; merge propagated to later groups
//   by key-rewrite mapping (key==k_o -> wkey), applied in merge order so
//   chains resolve transitively. Self slot reproduces the reference's
//   zero-persistence (v,v) pair. LDS writes inline (no reader until next
//   batch's Phase A; same-wave DS ordering guarantees visibility).
// ---------------------------------------------------------------------------
__global__ void __launch_bounds__(64) uf_kernel(const int* __restrict__ POS,
                                                const int* __restrict__ ORD,
                                                int* __restrict__ BI, int* __restrict__ DI) {
    __shared__ int2 pb[NPIX];   // {parent, pos}; pos static
    __shared__ int ordA[NPIX];
    int lane = threadIdx.x;
    int task = blockIdx.x;
    int feat = task >> 7;
    int dir = (task >> 6) & 1;
    int m = task & 63;
    const int* gpos = POS + task * NPIX;
    const int* gord = ORD + task * NPIX;
    for (int s = lane; s < NPIX; s += 64) {
        pb[s] = make_int2(s, gpos[s]);
        ordA[s] = gord[s];
    }
    __syncthreads();

    int base_out = ((feat * NIMG + m) * 2 + dir) * NPIX;
    int* bi = BI + base_out;
    int* di = DI + base_out;
    int k = 0;
    const int nn = dir ? 8 : 4;
    // packed dx/dy (+1, 2 bits each) for offsets {-1,0},{1,0},{0,-1},{0,1},
    // {-1,-1},{-1,1},{1,-1},{1,1}
    const unsigned DXP = 41048u;  // 0,2,1,1,0,0,2,2
    const unsigned DYP = 34949u;  // 1,1,0,2,0,2,0,2
    int groupId = lane / 9;       // 0..6 live; lane 63 -> 7 (inactive)
    int o = lane - groupId * 9;   // 0..8
    int dx = ((DXP >> (2 * (o & 7))) & 3) - 1;
    int dy = ((DYP >> (2 * (o & 7))) & 3) - 1;
    const int INVALID = 0x40000000 | lane;  // unique per lane, bit30 set

    for (int rb = 1; rb < NPIX; rb += 7) {
        int rj = rb + groupId;
        bool activeV = (groupId < 7) && (rj < NPIX);
        int vv = ordA[activeV ? rj : 0];

        // ---- Phase A: parallel root finding vs batch-start state ----
        int key = INVALID;
        if (activeV) {
            if (o == 8) {
                key = (rj << 10) | vv;           // self candidate (youngest)
            } else if (o < nn) {
                int vi = vv / HW, vj2 = vv % HW;
                int ui = vi + dx, uj = vj2 + dy;
                if ((unsigned)ui < (unsigned)HW && (unsigned)uj < (unsigned)HW) {
                    int x = ui * HW + uj;
                    int2 e = pb[x];
                    if (e.y < rj) {              // neighbor already added
                        while (e.x != x) {
                            int p = e.x;
                            int2 ep = pb[p];
                            if (ep.x != p) pb[x].x = ep.x;  // compress
                            x = p; e = ep;
                        }
                        key = (e.y << 10) | x;   // (root birth-pos, root)
                    }
                }
            }
        }

        // ---- Phase B: serial in-register resolution, j = 0..6 ----
        for (int j = 0; j < 7; ++j) {
            if (rb + j >= NPIX) break;           // wave-uniform
            int base = j * 9;
            int k0 = __builtin_amdgcn_readlane(key, base + 0);
            int k1 = __builtin_amdgcn_readlane(key, base + 1);
            int k2 = __builtin_amdgcn_readlane(key, base + 2);
            int k3 = __builtin_amdgcn_readlane(key, base + 3);
            int k4 = __builtin_amdgcn_readlane(key, base + 4);
            int k5 = __builtin_amdgcn_readlane(key, base + 5);
            int k6 = __builtin_amdgcn_readlane(key, base + 6);
            int k7 = __builtin_amdgcn_readlane(key, base + 7);
            int k8 = __builtin_amdgcn_readlane(key, base + 8);
            int wkey = min(min(min(min(k0, k1), min(k2, k3)),
                               min(min(k4, k5), min(k6, k7))), k8);
            int wroot = wkey & 1023;

            // dedupe: drop lanes whose key equals an earlier offset's key
            bool dup = false;
            if (o > 0 && key == k0) dup = true;
            if (o > 1 && key == k1) dup = true;
            if (o > 2 && key == k2) dup = true;
            if (o > 3 && key == k3) dup = true;
            if (o > 4 && key == k4) dup = true;
            if (o > 5 && key == k5) dup = true;
            if (o > 6 && key == k6) dup = true;
            if (o > 7 && key == k7) dup = true;

            bool emit = (groupId == j) && (key < 0x40000000) &&
                        (key != wkey) && !dup;
            unsigned long long em = __ballot(emit);
            if (emit) {
                int slot = k + (int)__popcll(em & ((1ull << lane) - 1ull));
                int root = key & 1023;
                if (dir == 0) { bi[slot] = root; di[slot] = vv; }
                else          { bi[slot] = vv;   di[slot] = root; }
                pb[root].x = wroot;              // link loser -> winner
            }
            k += (int)__popcll(em);

            // mapping: rewrite merged roots for later groups (ordered, so
            // chains a->b then b->c resolve transitively)
            key = (key == k0) ? wkey : key;
            key = (key == k1) ? wkey : key;
            key = (key == k2) ? wkey : key;
            key = (key == k3) ? wkey : key;
            key = (key == k4) ? wkey : key;
            key = (key == k5) ? wkey : key;
            key = (key == k6) ? wkey : key;
            key = (key == k7) ? wkey : key;
            key = (key == k8) ? wkey : key;
        }
    }
    // zero-pad unused slots (matches reference zeros; (0,0) tents are 0)
    for (int s = k + lane; s < NPIX; s += 64) { bi[s] = 0; di[s] = 0; }
}

// ---------------------------------------------------------------------------
// Kernel 6: persistence landscape. block = feat*128 + m*2 + h.
// ---------------------------------------------------------------------------
__global__ void landscape_kernel(const float* __restrict__ F,
                                 const int* __restrict__ BI, const int* __restrict__ DI,
                                 float* __restrict__ LAM1, float* __restrict__ LAM2) {
    __shared__ float bb[NPIX], dd[NPIX];
    int blk = blockIdx.x;
    int feat = blk >> 7;
    int m = (blk >> 1) & 63;
    int h = blk & 1;
    const float* fr = F + feat * NIMG * NPIX + m * NPIX;
    int base = ((feat * NIMG + m) * 2 + h) * NPIX;
    for (int p = threadIdx.x; p < NPIX; p += blockDim.x) {
        bb[p] = fr[BI[base + p]];
        dd[p] = fr[DI[base + p]];
    }
    __syncthreads();
    if (threadIdx.x < 32) {
        int t = threadIdx.x;
        float start = (feat == 0) ? 0.f : 1.f;
        float end = (feat == 0) ? 7.f : 8.f;
        float tv = start + (end - start) * ((float)t / 31.f);
        float v0 = 0.f, v1 = 0.f, v2 = 0.f;
        for (int p = 0; p < NPIX; ++p) {
            float tent = fmaxf(fminf(tv - bb[p], dd[p] - tv), 0.f);
            if (tent > v0)      { v2 = v1; v1 = v0; v0 = tent; }
            else if (tent > v1) { v2 = v1; v1 = tent; }
            else if (tent > v2) { v2 = tent; }
        }
        if (feat == 0) {
            float* lam = LAM1 + m * 128 + h * 64;
            lam[0 * 32 + t] = v0;
            lam[1 * 32 + t] = v1;
        } else {
            float* lam = LAM2 + m * 192 + h * 96;
            lam[0 * 32 + t] = v0;
            lam[1 * 32 + t] = v1;
            lam[2 * 32 + t] = v2;
        }
    }
}

// ---------------------------------------------------------------------------
// Kernel 7: MLP head. One block (64 threads) per image.
// ---------------------------------------------------------------------------
__global__ void mlp_kernel(const float* __restrict__ LAM1, const float* __restrict__ LAM2,
                           const float* __restrict__ w1, const float* __restrict__ b1,
                           const float* __restrict__ w2, const float* __restrict__ b2,
                           const float* __restrict__ wf, const float* __restrict__ bf,
                           float* __restrict__ out) {
    __shared__ float xc[64];
    int m = blockIdx.x;
    int n = threadIdx.x;
    if (n < 32) {
        float acc = b1[n];
        const float* l = LAM1 + m * 128;
        for (int c = 0; c < 128; ++c) acc += w1[n * 128 + c] * l[c];
        xc[n] = fmaxf(acc, 0.f);
    } else {
        int n2 = n - 32;
        float acc = b2[n2];
        const float* l = LAM2 + m * 192;
        for (int c = 0; c < 192; ++c) acc += w2[n2 * 192 + c] * l[c];
        xc[n] = fmaxf(acc, 0.f);
    }
    __syncthreads();
    if (n < 10) {
        float acc = bf[n];
        for (int c = 0; c < 64; ++c) acc += wf[n * 64 + c] * xc[c];
        out[m * 10 + n] = acc;
    }
}

extern "C" void kernel_launch(void* const* d_in, const int* in_sizes, int n_in,
                              void* d_out, int out_size, void* d_ws, size_t ws_size,
                              hipStream_t stream) {
    const float* x  = (const float*)d_in[0];
    const float* w1 = (const float*)d_in[1];
    const float* b1 = (const float*)d_in[2];
    const float* w2 = (const float*)d_in[3];
    const float* b2 = (const float*)d_in[4];
    const float* wf = (const float*)d_in[5];
    const float* bf = (const float*)d_in[6];
    float* out = (float*)d_out;

    char* ws = (char*)d_ws;
    size_t off = 0;
    unsigned short* SORT = (unsigned short*)(ws + off); off += (size_t)NPIX * NPIX * 2;
    unsigned short* D2S  = (unsigned short*)(ws + off); off += (size_t)NPIX * NPIX * 2;
    float* SUMS = (float*)(ws + off); off += 256;
    float* F    = (float*)(ws + off); off += (size_t)2 * NIMG * NPIX * 4;
    int* POS    = (int*)(ws + off);   off += (size_t)256 * NPIX * 4;
    int* ORD    = (int*)(ws + off);   off += (size_t)256 * NPIX * 4;
    int* BI     = (int*)(ws + off);   off += (size_t)256 * NPIX * 4;
    int* DI     = (int*)(ws + off);   off += (size_t)256 * NPIX * 4;
    float* LAM1 = (float*)(ws + off); off += (size_t)NIMG * 128 * 4;
    float* LAM2 = (float*)(ws + off); off += (size_t)NIMG * 192 * 4;

    build_consts_kernel<<<NPIX, 256, 0, stream>>>(SORT, D2S);
    row_sum_kernel<<<NIMG, 256, 0, stream>>>(x, SUMS);
    dtm_kernel<<<(NIMG * NPIX) / 4, 256, 0, stream>>>(x, SORT, D2S, SUMS, F);
    rank_kernel<<<256, 256, 0, stream>>>(F, POS, ORD);
    uf_kernel<<<256, 64, 0, stream>>>(POS, ORD, BI, DI);
    landscape_kernel<<<256, 256, 0, stream>>>(F, BI, DI, LAM1, LAM2);
    mlp_kernel<<<NIMG, 64, 0, stream>>>(LAM1, LAM2, w1, b1, w2, b2, wf, bf, out);
}

// Round 5
// 589.681 us; speedup vs baseline: 3.3794x; 1.1786x over previous
//
#include <hip/hip_runtime.h>

#define HW 28
#define NPIX 784   // 28*28
#define NIMG 64

// ---------------------------------------------------------------------------
// Kernel 1: grid distance-sort constants.
// ---------------------------------------------------------------------------
__global__ void build_consts_kernel(unsigned short* __restrict__ sortIdx,
                                    unsigned short* __restrict__ d2s) {
    __shared__ int d2[NPIX];
    int i = blockIdx.x;
    int ii = i / HW, ij = i % HW;
    for (int j = threadIdx.x; j < NPIX; j += blockDim.x) {
        int di = ii - j / HW;
        int dj = ij - j % HW;
        d2[j] = di * di + dj * dj;
    }
    __syncthreads();
    for (int j = threadIdx.x; j < NPIX; j += blockDim.x) {
        int dj2 = d2[j];
        int rank = 0;
        for (int q = 0; q < NPIX; ++q) {
            int dq = d2[q];
            rank += (dq < dj2) || (dq == dj2 && q < j);
        }
        sortIdx[i * NPIX + rank] = (unsigned short)j;
        d2s[i * NPIX + rank] = (unsigned short)dj2;
    }
}

// ---------------------------------------------------------------------------
// Kernel 2: per-image sums (for the DTM mass bound).
// ---------------------------------------------------------------------------
__global__ void row_sum_kernel(const float* __restrict__ x, float* __restrict__ sums) {
    int m = blockIdx.x;
    float acc = 0.f;
    for (int j = threadIdx.x; j < NPIX; j += blockDim.x) acc += x[m * NPIX + j];
    for (int off = 32; off > 0; off >>= 1) acc += __shfl_down(acc, off, 64);
    __shared__ float red[4];
    int lane = threadIdx.x & 63, w = threadIdx.x >> 6;
    if (lane == 0) red[w] = acc;
    __syncthreads();
    if (threadIdx.x == 0) sums[m] = red[0] + red[1] + red[2] + red[3];
}

// ---------------------------------------------------------------------------
// Kernel 3: DTM. One wave per (m, i). 2 elements/lane per scan chunk.
// ---------------------------------------------------------------------------
__global__ void dtm_kernel(const float* __restrict__ x,
                           const unsigned short* __restrict__ sortIdx,
                           const unsigned short* __restrict__ d2s,
                           const float* __restrict__ sums,
                           float* __restrict__ F) {
    int wid = blockIdx.x * 4 + (threadIdx.x >> 6);
    int lane = threadIdx.x & 63;
    int m = wid / NPIX;
    int i = wid % NPIX;
    if (m >= NIMG) return;
    float s = sums[m];
    float bound1 = 0.05f * s, bound2 = 0.2f * s;
    const float* xr = x + m * NPIX;
    const unsigned short* si = sortIdx + (size_t)i * NPIX;
    const unsigned short* dr = d2s + (size_t)i * NPIX;
    float carry = 0.f, acc1 = 0.f, acc2 = 0.f;
    for (int c = 0; c < 7; ++c) {
        int j0 = c * 128 + lane * 2;
        float w0 = 0.f, w1 = 0.f, d0 = 0.f, d1 = 0.f;
        if (j0 < NPIX) {
            ushort2 sv = *(const ushort2*)(si + j0);
            ushort2 dv = *(const ushort2*)(dr + j0);
            w0 = xr[sv.x]; w1 = xr[sv.y];
            d0 = (float)dv.x; d1 = (float)dv.y;
        }
        float ps = w0 + w1;
        float v = ps;
        for (int off = 1; off < 64; off <<= 1) {
            float t = __shfl_up(v, off, 64);
            if (lane >= off) v += t;
        }
        float cum0 = carry + v - ps;
        float cum1 = cum0 + w0;
        acc1 += fminf(fmaxf(bound1 - cum0, 0.f), w0) * d0
              + fminf(fmaxf(bound1 - cum1, 0.f), w1) * d1;
        acc2 += fminf(fmaxf(bound2 - cum0, 0.f), w0) * d0
              + fminf(fmaxf(bound2 - cum1, 0.f), w1) * d1;
        carry += __shfl(v, 63, 64);
    }
    for (int off = 32; off > 0; off >>= 1) {
        acc1 += __shfl_down(acc1, off, 64);
        acc2 += __shfl_down(acc2, off, 64);
    }
    if (lane == 0) {
        F[0 * NIMG * NPIX + m * NPIX + i] = sqrtf(acc1 / bound1);
        F[1 * NIMG * NPIX + m * NPIX + i] = sqrtf(acc2 / bound2);
    }
}

// ---------------------------------------------------------------------------
// Kernel 4: stable ranks. task = feat*128 + dir*64 + m.
// ---------------------------------------------------------------------------
__global__ void rank_kernel(const float* __restrict__ F,
                            int* __restrict__ POS, int* __restrict__ ORD) {
    __shared__ float fv[NPIX];
    int task = blockIdx.x;
    int feat = task >> 7;
    int dir = (task >> 6) & 1;
    int m = task & 63;
    const float* fr = F + feat * NIMG * NPIX + m * NPIX;
    for (int j = threadIdx.x; j < NPIX; j += blockDim.x) fv[j] = fr[j];
    __syncthreads();
    int* pos = POS + task * NPIX;
    int* ord = ORD + task * NPIX;
    for (int i = threadIdx.x; i < NPIX; i += blockDim.x) {
        float fi = fv[i];
        int rank = 0;
        if (dir == 0) {
            for (int q = 0; q < NPIX; ++q) {
                float fq = fv[q];
                rank += (fq < fi) || (fq == fi && q < i);
            }
        } else {
            for (int q = 0; q < NPIX; ++q) {
                float fq = fv[q];
                rank += (fq > fi) || (fq == fi && q < i);
            }
        }
        pos[i] = rank;
        ord[rank] = i;
    }
}

// ---------------------------------------------------------------------------
// Kernel 5: fused union-find + landscape. One wave per task.
// Fast path: all valid neighbor roots identical -> just link v (no pair:
//   the reference's (v,v) self pair and (0,0) padding have tent == 0).
// Slow path (rare, wave-uniform branch): re-find group keys against the
//   CURRENT LDS state (absorbs all staleness from earlier in-batch merges),
//   min -> winner (oldest root), dedupe, emit (F[b],F[d]) pairs to LDS,
//   link losers & v to winner. Pair SET == reference's nonzero-persistence
//   set (order-invariant elder rule; root == oldest member invariant).
// ---------------------------------------------------------------------------
template<int NN>   // NN = 4 (dir 0) or 8 (dir 1) neighbor slots per group
__device__ int uf_run(int2* pb, const int* ordA, const float* fv,
                      float2* pairs, int dir) {
    const int lane = threadIdx.x;
    const int GB = 64 / NN;          // vertices per batch
    const int g = lane / NN;         // group id
    const int o = lane % NN;         // neighbor slot
    // packed dx/dy (+1, 2 bits each) for {-1,0},{1,0},{0,-1},{0,1},
    // {-1,-1},{-1,1},{1,-1},{1,1}
    const unsigned DXP = 41048u;
    const unsigned DYP = 34949u;
    int dx = ((DXP >> (2 * o)) & 3) - 1;
    int dy = ((DYP >> (2 * o)) & 3) - 1;
    const int INVALID = 0x7fffffff;
    int k = 0;

    for (int rb = 1; rb < NPIX; rb += GB) {
        int rj = rb + g;
        bool act = (rj < NPIX);
        int vv = ordA[act ? rj : 0];

        // ---- Phase A: parallel root find vs batch-start state ----
        int key = INVALID;
        if (act) {
            int vi = vv / HW, vj2 = vv % HW;
            int ui = vi + dx, uj = vj2 + dy;
            if ((unsigned)ui < (unsigned)HW && (unsigned)uj < (unsigned)HW) {
                int x = ui * HW + uj;
                int2 e = pb[x];
                if (e.y < rj) {                      // neighbor already added
                    while (e.x != x) {
                        int p = e.x;
                        int2 ep = pb[p];
                        if (ep.x != p) pb[x].x = ep.x;  // compress
                        x = p; e = ep;
                    }
                    key = (e.y << 10) | x;           // (root pos, root)
                }
            }
        }

        // ---- Phase B: per-group resolution ----
        for (int j = 0; j < GB; ++j) {
            if (rb + j >= NPIX) break;               // wave-uniform
            int kk[NN];
            #pragma unroll
            for (int t = 0; t < NN; ++t)
                kk[t] = __builtin_amdgcn_readlane(key, j * NN + t);
            int wmin = kk[0];
            #pragma unroll
            for (int t = 1; t < NN; ++t) wmin = min(wmin, kk[t]);
            if (wmin == INVALID) continue;           // isolated vertex
            bool slow = false;
            #pragma unroll
            for (int t = 0; t < NN; ++t)
                slow = slow || (kk[t] != INVALID && kk[t] != wmin);

            if (!slow) {
                // single component: just link v into it
                int wroot = wmin & 1023;
                if (lane == j * NN) pb[vv].x = wroot;
            } else {
                // re-find this group's keys against CURRENT state
                int rkey = key;
                if (g == j && key != INVALID) {
                    int x = key & 1023;
                    int2 e = pb[x];
                    while (e.x != x) {
                        int p = e.x;
                        int2 ep = pb[p];
                        if (ep.x != p) pb[x].x = ep.x;
                        x = p; e = ep;
                    }
                    rkey = (e.y << 10) | x;
                }
                int kr[NN];
                #pragma unroll
                for (int t = 0; t < NN; ++t)
                    kr[t] = __builtin_amdgcn_readlane(rkey, j * NN + t);
                int wmin2 = kr[0];
                #pragma unroll
                for (int t = 1; t < NN; ++t) wmin2 = min(wmin2, kr[t]);
                int wroot = wmin2 & 1023;

                bool emit = (g == j) && (rkey != INVALID) && (rkey != wmin2);
                #pragma unroll
                for (int t = 0; t < NN; ++t)
                    if (t < o && kr[t] == rkey) emit = false;   // dedupe

                unsigned long long em = __ballot(emit);
                if (emit) {
                    int slot = k + (int)__popcll(em & ((1ull << lane) - 1ull));
                    int root = rkey & 1023;
                    float fb = fv[root], fd = fv[vv];
                    pairs[slot] = dir ? make_float2(fd, fb)
                                      : make_float2(fb, fd);
                    pb[root].x = wroot;              // loser -> winner
                }
                k += (int)__popcll(em);
                if (lane == j * NN) pb[vv].x = wroot;
            }
        }
    }
    return k;
}

__global__ void __launch_bounds__(64) uf_land_kernel(const int* __restrict__ POS,
                                                     const int* __restrict__ ORD,
                                                     const float* __restrict__ F,
                                                     float* __restrict__ LAM1,
                                                     float* __restrict__ LAM2) {
    __shared__ int2 pb[NPIX];       // {parent, pos}; pos static
    __shared__ int ordA[NPIX];
    __shared__ float fv[NPIX];      // this task's DTM values
    __shared__ float2 pairs[NPIX];  // (b, d) values of real pairs
    int lane = threadIdx.x;
    int task = blockIdx.x;
    int feat = task >> 7;
    int dir = (task >> 6) & 1;
    int m = task & 63;
    const int* gpos = POS + task * NPIX;
    const int* gord = ORD + task * NPIX;
    const float* fr = F + feat * NIMG * NPIX + m * NPIX;
    for (int s = lane; s < NPIX; s += 64) {
        pb[s] = make_int2(s, gpos[s]);
        ordA[s] = gord[s];
        fv[s] = fr[s];
    }
    __syncthreads();

    int k;
    if (dir == 0) k = uf_run<4>(pb, ordA, fv, pairs, dir);
    else          k = uf_run<8>(pb, ordA, fv, pairs, dir);

    __syncthreads();

    // ---- fused landscape: top-3 tents over the k real pairs ----
    if (lane < 32) {
        int t = lane;
        float start = (feat == 0) ? 0.f : 1.f;
        float end   = (feat == 0) ? 7.f : 8.f;
        float tv = start + (end - start) * ((float)t / 31.f);
        float v0 = 0.f, v1 = 0.f, v2 = 0.f;
        for (int p = 0; p < k; ++p) {
            float2 bd = pairs[p];
            float tent = fmaxf(fminf(tv - bd.x, bd.y - tv), 0.f);
            if (tent > v0)      { v2 = v1; v1 = v0; v0 = tent; }
            else if (tent > v1) { v2 = v1; v1 = tent; }
            else if (tent > v2) { v2 = tent; }
        }
        if (feat == 0) {
            float* lam = LAM1 + m * 128 + dir * 64;
            lam[0 * 32 + t] = v0;
            lam[1 * 32 + t] = v1;
        } else {
            float* lam = LAM2 + m * 192 + dir * 96;
            lam[0 * 32 + t] = v0;
            lam[1 * 32 + t] = v1;
            lam[2 * 32 + t] = v2;
        }
    }
}

// ---------------------------------------------------------------------------
// Kernel 6: MLP head. One block (64 threads) per image.
// ---------------------------------------------------------------------------
__global__ void mlp_kernel(const float* __restrict__ LAM1, const float* __restrict__ LAM2,
                           const float* __restrict__ w1, const float* __restrict__ b1,
                           const float* __restrict__ w2, const float* __restrict__ b2,
                           const float* __restrict__ wf, const float* __restrict__ bf,
                           float* __restrict__ out) {
    __shared__ float xc[64];
    int m = blockIdx.x;
    int n = threadIdx.x;
    if (n < 32) {
        float acc = b1[n];
        const float* l = LAM1 + m * 128;
        for (int c = 0; c < 128; ++c) acc += w1[n * 128 + c] * l[c];
        xc[n] = fmaxf(acc, 0.f);
    } else {
        int n2 = n - 32;
        float acc = b2[n2];
        const float* l = LAM2 + m * 192;
        for (int c = 0; c < 192; ++c) acc += w2[n2 * 192 + c] * l[c];
        xc[n] = fmaxf(acc, 0.f);
    }
    __syncthreads();
    if (n < 10) {
        float acc = bf[n];
        for (int c = 0; c < 64; ++c) acc += wf[n * 64 + c] * xc[c];
        out[m * 10 + n] = acc;
    }
}

extern "C" void kernel_launch(void* const* d_in, const int* in_sizes, int n_in,
                              void* d_out, int out_size, void* d_ws, size_t ws_size,
                              hipStream_t stream) {
    const float* x  = (const float*)d_in[0];
    const float* w1 = (const float*)d_in[1];
    const float* b1 = (const float*)d_in[2];
    const float* w2 = (const float*)d_in[3];
    const float* b2 = (const float*)d_in[4];
    const float* wf = (const float*)d_in[5];
    const float* bf = (const float*)d_in[6];
    float* out = (float*)d_out;

    char* ws = (char*)d_ws;
    size_t off = 0;
    unsigned short* SORT = (unsigned short*)(ws + off); off += (size_t)NPIX * NPIX * 2;
    unsigned short* D2S  = (unsigned short*)(ws + off); off += (size_t)NPIX * NPIX * 2;
    float* SUMS = (float*)(ws + off); off += 256;
    float* F    = (float*)(ws + off); off += (size_t)2 * NIMG * NPIX * 4;
    int* POS    = (int*)(ws + off);   off += (size_t)256 * NPIX * 4;
    int* ORD    = (int*)(ws + off);   off += (size_t)256 * NPIX * 4;
    float* LAM1 = (float*)(ws + off); off += (size_t)NIMG * 128 * 4;
    float* LAM2 = (float*)(ws + off); off += (size_t)NIMG * 192 * 4;

    build_consts_kernel<<<NPIX, 256, 0, stream>>>(SORT, D2S);
    row_sum_kernel<<<NIMG, 256, 0, stream>>>(x, SUMS);
    dtm_kernel<<<(NIMG * NPIX) / 4, 256, 0, stream>>>(x, SORT, D2S, SUMS, F);
    rank_kernel<<<256, 256, 0, stream>>>(F, POS, ORD);
    uf_land_kernel<<<256, 64, 0, stream>>>(POS, ORD, F, LAM1, LAM2);
    mlp_kernel<<<NIMG, 64, 0, stream>>>(LAM1, LAM2, w1, b1, w2, b2, wf, bf, out);
}

// Round 6
// 471.136 us; speedup vs baseline: 4.2297x; 1.2516x over previous
//
#include <hip/hip_runtime.h>

#define HW 28
#define NPIX 784   // 28*28
#define NIMG 64

// ---------------------------------------------------------------------------
// Kernel 1: grid distance-sort constants.
// ---------------------------------------------------------------------------
__global__ void build_consts_kernel(unsigned short* __restrict__ sortIdx,
                                    unsigned short* __restrict__ d2s) {
    __shared__ int d2[NPIX];
    int i = blockIdx.x;
    int ii = i / HW, ij = i % HW;
    for (int j = threadIdx.x; j < NPIX; j += blockDim.x) {
        int di = ii - j / HW;
        int dj = ij - j % HW;
        d2[j] = di * di + dj * dj;
    }
    __syncthreads();
    for (int j = threadIdx.x; j < NPIX; j += blockDim.x) {
        int dj2 = d2[j];
        int rank = 0;
        for (int q = 0; q < NPIX; ++q) {
            int dq = d2[q];
            rank += (dq < dj2) || (dq == dj2 && q < j);
        }
        sortIdx[i * NPIX + rank] = (unsigned short)j;
        d2s[i * NPIX + rank] = (unsigned short)dj2;
    }
}

// ---------------------------------------------------------------------------
// Kernel 2: per-image sums (for the DTM mass bound).
// ---------------------------------------------------------------------------
__global__ void row_sum_kernel(const float* __restrict__ x, float* __restrict__ sums) {
    int m = blockIdx.x;
    float acc = 0.f;
    for (int j = threadIdx.x; j < NPIX; j += blockDim.x) acc += x[m * NPIX + j];
    for (int off = 32; off > 0; off >>= 1) acc += __shfl_down(acc, off, 64);
    __shared__ float red[4];
    int lane = threadIdx.x & 63, w = threadIdx.x >> 6;
    if (lane == 0) red[w] = acc;
    __syncthreads();
    if (threadIdx.x == 0) sums[m] = red[0] + red[1] + red[2] + red[3];
}

// ---------------------------------------------------------------------------
// Kernel 3: DTM. One wave per (m, i). 2 elements/lane per scan chunk.
// ---------------------------------------------------------------------------
__global__ void dtm_kernel(const float* __restrict__ x,
                           const unsigned short* __restrict__ sortIdx,
                           const unsigned short* __restrict__ d2s,
                           const float* __restrict__ sums,
                           float* __restrict__ F) {
    int wid = blockIdx.x * 4 + (threadIdx.x >> 6);
    int lane = threadIdx.x & 63;
    int m = wid / NPIX;
    int i = wid % NPIX;
    if (m >= NIMG) return;
    float s = sums[m];
    float bound1 = 0.05f * s, bound2 = 0.2f * s;
    const float* xr = x + m * NPIX;
    const unsigned short* si = sortIdx + (size_t)i * NPIX;
    const unsigned short* dr = d2s + (size_t)i * NPIX;
    float carry = 0.f, acc1 = 0.f, acc2 = 0.f;
    for (int c = 0; c < 7; ++c) {
        int j0 = c * 128 + lane * 2;
        float w0 = 0.f, w1 = 0.f, d0 = 0.f, d1 = 0.f;
        if (j0 < NPIX) {
            ushort2 sv = *(const ushort2*)(si + j0);
            ushort2 dv = *(const ushort2*)(dr + j0);
            w0 = xr[sv.x]; w1 = xr[sv.y];
            d0 = (float)dv.x; d1 = (float)dv.y;
        }
        float ps = w0 + w1;
        float v = ps;
        for (int off = 1; off < 64; off <<= 1) {
            float t = __shfl_up(v, off, 64);
            if (lane >= off) v += t;
        }
        float cum0 = carry + v - ps;
        float cum1 = cum0 + w0;
        acc1 += fminf(fmaxf(bound1 - cum0, 0.f), w0) * d0
              + fminf(fmaxf(bound1 - cum1, 0.f), w1) * d1;
        acc2 += fminf(fmaxf(bound2 - cum0, 0.f), w0) * d0
              + fminf(fmaxf(bound2 - cum1, 0.f), w1) * d1;
        carry += __shfl(v, 63, 64);
    }
    for (int off = 32; off > 0; off >>= 1) {
        acc1 += __shfl_down(acc1, off, 64);
        acc2 += __shfl_down(acc2, off, 64);
    }
    if (lane == 0) {
        F[0 * NIMG * NPIX + m * NPIX + i] = sqrtf(acc1 / bound1);
        F[1 * NIMG * NPIX + m * NPIX + i] = sqrtf(acc2 / bound2);
    }
}

// ---------------------------------------------------------------------------
// Kernel 4: stable ranks. task = feat*128 + dir*64 + m.
// ---------------------------------------------------------------------------
__global__ void rank_kernel(const float* __restrict__ F,
                            int* __restrict__ POS, int* __restrict__ ORD) {
    __shared__ float fv[NPIX];
    int task = blockIdx.x;
    int feat = task >> 7;
    int dir = (task >> 6) & 1;
    int m = task & 63;
    const float* fr = F + feat * NIMG * NPIX + m * NPIX;
    for (int j = threadIdx.x; j < NPIX; j += blockDim.x) fv[j] = fr[j];
    __syncthreads();
    int* pos = POS + task * NPIX;
    int* ord = ORD + task * NPIX;
    for (int i = threadIdx.x; i < NPIX; i += blockDim.x) {
        float fi = fv[i];
        int rank = 0;
        if (dir == 0) {
            for (int q = 0; q < NPIX; ++q) {
                float fq = fv[q];
                rank += (fq < fi) || (fq == fi && q < i);
            }
        } else {
            for (int q = 0; q < NPIX; ++q) {
                float fq = fv[q];
                rank += (fq > fi) || (fq == fi && q < i);
            }
        }
        pos[i] = rank;
        ord[rank] = i;
    }
}

// ---------------------------------------------------------------------------
// Kernel 5: fused union-find + landscape. One wave per task.
// Phase A: read-only parallel find (keys vs batch-start state).
// Phase B: 100% register-resident resolution. Per group j (unrolled):
//   kk = readlanes (SGPR), winner = min; selfkey remap (1 cndmask) covers
//   the common in-batch-adjacency case; full NN-deep remap only on the rare
//   multi-component step (still register-only — no LDS re-find).
// Pairs stored packed (root | v<<10), converted to (F[b],F[d]) afterward.
// Pair SET == reference's nonzero-persistence set (order-invariant elder
// rule; (v,v) self pairs and (0,0) padding have tent == 0).
// ---------------------------------------------------------------------------
template<int NN>   // NN = 4 (dir 0) or 8 (dir 1)
__device__ int uf_run(int2* pb, const int* ordA, int* pairsI) {
    const int lane = threadIdx.x;
    const int GB = 64 / NN;          // vertices per batch
    const int g = lane / NN;         // group id
    const int o = lane % NN;         // neighbor slot
    // packed dx/dy (+1, 2 bits each) for {-1,0},{1,0},{0,-1},{0,1},
    // {-1,-1},{-1,1},{1,-1},{1,1}
    const unsigned DXP = 41048u;
    const unsigned DYP = 34949u;
    const int dx = ((DXP >> (2 * o)) & 3) - 1;
    const int dy = ((DYP >> (2 * o)) & 3) - 1;
    const int INVALID = 0x100000 | lane;   // > any valid key, unique per lane
    const unsigned long long lmask = (1ull << lane) - 1ull;
    int k = 0;

    for (int rb = 1; rb < NPIX; rb += GB) {
        int rj = rb + g;
        bool act = (rj < NPIX);
        int vv = ordA[act ? rj : 0];

        // ---- Phase A: parallel read-only root find ----
        int key = INVALID;
        if (act) {
            int vi = vv / HW, vj2 = vv % HW;
            int ui = vi + dx, uj = vj2 + dy;
            if ((unsigned)ui < (unsigned)HW && (unsigned)uj < (unsigned)HW) {
                int x = ui * HW + uj;
                int2 e = pb[x];
                if (e.y < rj) {                  // neighbor already added
                    while (e.x != x) { x = e.x; e = pb[x]; }
                    key = (e.y << 10) | x;       // (root pos, root)
                }
            }
        }

        // ---- Phase B: register-only resolution ----
        #pragma unroll
        for (int j = 0; j < GB; ++j) {
            if (rb + j >= NPIX) break;           // wave-uniform
            int kk[NN];
            #pragma unroll
            for (int t = 0; t < NN; ++t)
                kk[t] = __builtin_amdgcn_readlane(key, j * NN + t);
            int mn = kk[0];
            #pragma unroll
            for (int t = 1; t < NN; ++t) mn = min(mn, kk[t]);
            int vvj = __builtin_amdgcn_readlane(vv, j * NN);
            int sj = ((rb + j) << 10) | vvj;     // v_j's self key
            int tj = min(mn, sj);                // valid keys < sj always
            int troot = tj & 1023;

            bool slow = false;
            #pragma unroll
            for (int t = 0; t < NN; ++t)
                slow = slow || (kk[t] < 0x100000 && kk[t] != mn);

            if (slow) {                          // >1 distinct component
                bool emit = (g == j) && (key < 0x100000) && (key != mn);
                #pragma unroll
                for (int t = 0; t < NN; ++t)
                    if (t < o && kk[t] == key) emit = false;   // dedupe
                unsigned long long em = __ballot(emit);
                if (emit) {
                    int slot = k + (int)__popcll(em & lmask);
                    pairsI[slot] = (key & 1023) | (vvj << 10);
                    pb[key & 1023].x = troot;    // loser root -> winner
                }
                k += (int)__popcll(em);
                #pragma unroll
                for (int t = 0; t < NN; ++t)     // remap merged roots
                    key = (key == kk[t]) ? tj : key;
            }
            key = (key == sj) ? tj : key;        // in-batch self-root remap
            if (lane == j * NN) pb[vvj].x = troot;  // link v_j
        }
    }
    return k;
}

__global__ void __launch_bounds__(64) uf_land_kernel(const int* __restrict__ POS,
                                                     const int* __restrict__ ORD,
                                                     const float* __restrict__ F,
                                                     float* __restrict__ LAM1,
                                                     float* __restrict__ LAM2) {
    __shared__ int2 pb[NPIX];       // {parent, pos}; pos static
    __shared__ int ordA[NPIX];
    __shared__ float fv[NPIX];      // this task's DTM values
    __shared__ int pairsI[NPIX];    // packed (root | v<<10)
    __shared__ float2 pairs[NPIX];  // (b, d) values
    int lane = threadIdx.x;
    int task = blockIdx.x;
    int feat = task >> 7;
    int dir = (task >> 6) & 1;
    int m = task & 63;
    const int* gpos = POS + task * NPIX;
    const int* gord = ORD + task * NPIX;
    const float* fr = F + feat * NIMG * NPIX + m * NPIX;
    for (int s = lane; s < NPIX; s += 64) {
        pb[s] = make_int2(s, gpos[s]);
        ordA[s] = gord[s];
        fv[s] = fr[s];
    }
    __syncthreads();

    int k;
    if (dir == 0) k = uf_run<4>(pb, ordA, pairsI);
    else          k = uf_run<8>(pb, ordA, pairsI);
    __syncthreads();

    // convert packed pairs to (b, d) float values (dir 1 stores swapped)
    for (int s = lane; s < k; s += 64) {
        int p = pairsI[s];
        float fb = fv[p & 1023], fd = fv[p >> 10];
        pairs[s] = dir ? make_float2(fd, fb) : make_float2(fb, fd);
    }
    __syncthreads();

    // ---- fused landscape: top-3 tents over the k real pairs ----
    if (lane < 32) {
        int t = lane;
        float start = (feat == 0) ? 0.f : 1.f;
        float end   = (feat == 0) ? 7.f : 8.f;
        float tv = start + (end - start) * ((float)t / 31.f);
        float v0 = 0.f, v1 = 0.f, v2 = 0.f;
        for (int p = 0; p < k; ++p) {
            float2 bd = pairs[p];
            float tent = fmaxf(fminf(tv - bd.x, bd.y - tv), 0.f);
            if (tent > v0)      { v2 = v1; v1 = v0; v0 = tent; }
            else if (tent > v1) { v2 = v1; v1 = tent; }
            else if (tent > v2) { v2 = tent; }
        }
        if (feat == 0) {
            float* lam = LAM1 + m * 128 + dir * 64;
            lam[0 * 32 + t] = v0;
            lam[1 * 32 + t] = v1;
        } else {
            float* lam = LAM2 + m * 192 + dir * 96;
            lam[0 * 32 + t] = v0;
            lam[1 * 32 + t] = v1;
            lam[2 * 32 + t] = v2;
        }
    }
}

// ---------------------------------------------------------------------------
// Kernel 6: MLP head. One block (64 threads) per image.
// ---------------------------------------------------------------------------
__global__ void mlp_kernel(const float* __restrict__ LAM1, const float* __restrict__ LAM2,
                           const float* __restrict__ w1, const float* __restrict__ b1,
                           const float* __restrict__ w2, const float* __restrict__ b2,
                           const float* __restrict__ wf, const float* __restrict__ bf,
                           float* __restrict__ out) {
    __shared__ float xc[64];
    int m = blockIdx.x;
    int n = threadIdx.x;
    if (n < 32) {
        float acc = b1[n];
        const float* l = LAM1 + m * 128;
        for (int c = 0; c < 128; ++c) acc += w1[n * 128 + c] * l[c];
        xc[n] = fmaxf(acc, 0.f);
    } else {
        int n2 = n - 32;
        float acc = b2[n2];
        const float* l = LAM2 + m * 192;
        for (int c = 0; c < 192; ++c) acc += w2[n2 * 192 + c] * l[c];
        xc[n] = fmaxf(acc, 0.f);
    }
    __syncthreads();
    if (n < 10) {
        float acc = bf[n];
        for (int c = 0; c < 64; ++c) acc += wf[n * 64 + c] * xc[c];
        out[m * 10 + n] = acc;
    }
}

extern "C" void kernel_launch(void* const* d_in, const int* in_sizes, int n_in,
                              void* d_out, int out_size, void* d_ws, size_t ws_size,
                              hipStream_t stream) {
    const float* x  = (const float*)d_in[0];
    const float* w1 = (const float*)d_in[1];
    const float* b1 = (const float*)d_in[2];
    const float* w2 = (const float*)d_in[3];
    const float* b2 = (const float*)d_in[4];
    const float* wf = (const float*)d_in[5];
    const float* bf = (const float*)d_in[6];
    float* out = (float*)d_out;

    char* ws = (char*)d_ws;
    size_t off = 0;
    unsigned short* SORT = (unsigned short*)(ws + off); off += (size_t)NPIX * NPIX * 2;
    unsigned short* D2S  = (unsigned short*)(ws + off); off += (size_t)NPIX * NPIX * 2;
    float* SUMS = (float*)(ws + off); off += 256;
    float* F    = (float*)(ws + off); off += (size_t)2 * NIMG * NPIX * 4;
    int* POS    = (int*)(ws + off);   off += (size_t)256 * NPIX * 4;
    int* ORD    = (int*)(ws + off);   off += (size_t)256 * NPIX * 4;
    float* LAM1 = (float*)(ws + off); off += (size_t)NIMG * 128 * 4;
    float* LAM2 = (float*)(ws + off); off += (size_t)NIMG * 192 * 4;

    build_consts_kernel<<<NPIX, 256, 0, stream>>>(SORT, D2S);
    row_sum_kernel<<<NIMG, 256, 0, stream>>>(x, SUMS);
    dtm_kernel<<<(NIMG * NPIX) / 4, 256, 0, stream>>>(x, SORT, D2S, SUMS, F);
    rank_kernel<<<256, 256, 0, stream>>>(F, POS, ORD);
    uf_land_kernel<<<256, 64, 0, stream>>>(POS, ORD, F, LAM1, LAM2);
    mlp_kernel<<<NIMG, 64, 0, stream>>>(LAM1, LAM2, w1, b1, w2, b2, wf, bf, out);
}

// Round 7
// 343.648 us; speedup vs baseline: 5.7989x; 1.3710x over previous
//
#include <hip/hip_runtime.h>

#define HW 28
#define NPIX 784   // 28*28
#define NIMG 64
#define MAXD2 1459 // d2 <= 2*27^2 = 1458

// ---------------------------------------------------------------------------
// Kernel 1: grid distance-sort constants via LDS COUNTING SORT (O(N)/pixel).
// Tie order within a d2 bin is irrelevant for DTM: d2 constant within the
// bin makes the water-fill contribution order-invariant, so unstable atomic
// placement is exact.
// ---------------------------------------------------------------------------
__global__ void build_consts_kernel(unsigned short* __restrict__ sortIdx,
                                    unsigned short* __restrict__ d2s) {
    __shared__ int cnt[MAXD2];
    __shared__ int d2v[NPIX];
    __shared__ int wtot[4];
    int i = blockIdx.x;
    int tid = threadIdx.x;
    for (int b = tid; b < MAXD2; b += 256) cnt[b] = 0;
    __syncthreads();
    int ii = i / HW, ij = i % HW;
    for (int j = tid; j < NPIX; j += 256) {
        int di = ii - j / HW, dj = ij - j % HW;
        int d = di * di + dj * dj;
        d2v[j] = d;
        atomicAdd(&cnt[d], 1);
    }
    __syncthreads();
    // exclusive prefix over bins: 6 bins/thread, then wave+block scan
    int b0 = tid * 6;
    int lc[6];
    int s0 = 0;
    #pragma unroll
    for (int t = 0; t < 6; ++t) {
        int b = b0 + t;
        lc[t] = (b < MAXD2) ? cnt[b] : 0;
        s0 += lc[t];
    }
    int lane = tid & 63, wv = tid >> 6;
    int v = s0;
    for (int off = 1; off < 64; off <<= 1) {
        int t2 = __shfl_up(v, off, 64);
        if (lane >= off) v += t2;
    }
    if (lane == 63) wtot[wv] = v;
    __syncthreads();
    int wadd = 0;
    for (int w2 = 0; w2 < wv; ++w2) wadd += wtot[w2];
    int run = wadd + v - s0;           // exclusive prefix of this chunk
    __syncthreads();                   // cnt reads done above
    #pragma unroll
    for (int t = 0; t < 6; ++t) {
        int b = b0 + t;
        if (b < MAXD2) { cnt[b] = run; run += lc[t]; }
    }
    __syncthreads();
    for (int j = tid; j < NPIX; j += 256) {
        int d = d2v[j];
        int slot = atomicAdd(&cnt[d], 1);
        sortIdx[i * NPIX + slot] = (unsigned short)j;
        d2s[i * NPIX + slot] = (unsigned short)d;
    }
}

// ---------------------------------------------------------------------------
// Kernel 2: per-image sums (for the DTM mass bound).
// ---------------------------------------------------------------------------
__global__ void row_sum_kernel(const float* __restrict__ x, float* __restrict__ sums) {
    int m = blockIdx.x;
    float acc = 0.f;
    for (int j = threadIdx.x; j < NPIX; j += blockDim.x) acc += x[m * NPIX + j];
    for (int off = 32; off > 0; off >>= 1) acc += __shfl_down(acc, off, 64);
    __shared__ float red[4];
    int lane = threadIdx.x & 63, w = threadIdx.x >> 6;
    if (lane == 0) red[w] = acc;
    __syncthreads();
    if (threadIdx.x == 0) sums[m] = red[0] + red[1] + red[2] + red[3];
}

// ---------------------------------------------------------------------------
// Kernel 3: DTM. One wave per (m, i). EARLY EXIT once cum >= bound2 (all
// later eff terms are exactly 0 for both bounds since bound1 < bound2).
// ---------------------------------------------------------------------------
__global__ void dtm_kernel(const float* __restrict__ x,
                           const unsigned short* __restrict__ sortIdx,
                           const unsigned short* __restrict__ d2s,
                           const float* __restrict__ sums,
                           float* __restrict__ F) {
    int wid = blockIdx.x * 4 + (threadIdx.x >> 6);
    int lane = threadIdx.x & 63;
    int m = wid / NPIX;
    int i = wid % NPIX;
    if (m >= NIMG) return;
    float s = sums[m];
    float bound1 = 0.05f * s, bound2 = 0.2f * s;
    const float* xr = x + m * NPIX;
    const unsigned short* si = sortIdx + (size_t)i * NPIX;
    const unsigned short* dr = d2s + (size_t)i * NPIX;
    float carry = 0.f, acc1 = 0.f, acc2 = 0.f;
    for (int c = 0; c < 7; ++c) {
        int j0 = c * 128 + lane * 2;
        float w0 = 0.f, w1 = 0.f, d0 = 0.f, d1 = 0.f;
        if (j0 < NPIX) {
            ushort2 sv = *(const ushort2*)(si + j0);
            ushort2 dv = *(const ushort2*)(dr + j0);
            w0 = xr[sv.x]; w1 = xr[sv.y];
            d0 = (float)dv.x; d1 = (float)dv.y;
        }
        float ps = w0 + w1;
        float v = ps;
        for (int off = 1; off < 64; off <<= 1) {
            float t = __shfl_up(v, off, 64);
            if (lane >= off) v += t;
        }
        float cum0 = carry + v - ps;
        float cum1 = cum0 + w0;
        acc1 += fminf(fmaxf(bound1 - cum0, 0.f), w0) * d0
              + fminf(fmaxf(bound1 - cum1, 0.f), w1) * d1;
        acc2 += fminf(fmaxf(bound2 - cum0, 0.f), w0) * d0
              + fminf(fmaxf(bound2 - cum1, 0.f), w1) * d1;
        carry += __shfl(v, 63, 64);
        if (carry >= bound2) break;   // wave-uniform: all later eff == 0
    }
    for (int off = 32; off > 0; off >>= 1) {
        acc1 += __shfl_down(acc1, off, 64);
        acc2 += __shfl_down(acc2, off, 64);
    }
    if (lane == 0) {
        F[0 * NIMG * NPIX + m * NPIX + i] = sqrtf(acc1 / bound1);
        F[1 * NIMG * NPIX + m * NPIX + i] = sqrtf(acc2 / bound2);
    }
}

// ---------------------------------------------------------------------------
// Kernel 4: stable ranks. task = feat*128 + dir*64 + m.
// ---------------------------------------------------------------------------
__global__ void rank_kernel(const float* __restrict__ F,
                            int* __restrict__ POS, int* __restrict__ ORD) {
    __shared__ float fv[NPIX];
    int task = blockIdx.x;
    int feat = task >> 7;
    int dir = (task >> 6) & 1;
    int m = task & 63;
    const float* fr = F + feat * NIMG * NPIX + m * NPIX;
    for (int j = threadIdx.x; j < NPIX; j += blockDim.x) fv[j] = fr[j];
    __syncthreads();
    int* pos = POS + task * NPIX;
    int* ord = ORD + task * NPIX;
    for (int i = threadIdx.x; i < NPIX; i += blockDim.x) {
        float fi = fv[i];
        int rank = 0;
        if (dir == 0) {
            for (int q = 0; q < NPIX; ++q) {
                float fq = fv[q];
                rank += (fq < fi) || (fq == fi && q < i);
            }
        } else {
            for (int q = 0; q < NPIX; ++q) {
                float fq = fv[q];
                rank += (fq > fi) || (fq == fi && q < i);
            }
        }
        pos[i] = rank;
        ord[rank] = i;
    }
}

// ---------------------------------------------------------------------------
// Kernel 5: fused union-find + landscape. One wave per task.
// Phase A: parallel find WITH path-halving writes (lock-free; links only
//   move toward ancestors, so races are benign — keeps chains short).
// Phase B: 100% register-resident resolution (readlane + SALU min + cndmask
//   remap); next batch's ordA value prefetched during Phase B.
// ---------------------------------------------------------------------------
template<int NN>   // NN = 4 (dir 0) or 8 (dir 1)
__device__ int uf_run(int2* pb, const int* ordA, int* pairsI) {
    const int lane = threadIdx.x;
    const int GB = 64 / NN;          // vertices per batch
    const int g = lane / NN;         // group id
    const int o = lane % NN;         // neighbor slot
    // packed dx/dy (+1, 2 bits each) for {-1,0},{1,0},{0,-1},{0,1},
    // {-1,-1},{-1,1},{1,-1},{1,1}
    const unsigned DXP = 41048u;
    const unsigned DYP = 34949u;
    const int dx = ((DXP >> (2 * o)) & 3) - 1;
    const int dy = ((DYP >> (2 * o)) & 3) - 1;
    const int INVALID = 0x100000 | lane;   // > any valid key, unique per lane
    const unsigned long long lmask = (1ull << lane) - 1ull;
    int k = 0;

    int rj0 = 1 + g;
    int vv = ordA[(rj0 < NPIX) ? rj0 : 0];

    for (int rb = 1; rb < NPIX; rb += GB) {
        int rj = rb + g;
        bool act = (rj < NPIX);

        // ---- Phase A: parallel root find with halving ----
        int key = INVALID;
        if (act) {
            int vi = vv / HW, vj2 = vv % HW;
            int ui = vi + dx, uj = vj2 + dy;
            if ((unsigned)ui < (unsigned)HW && (unsigned)uj < (unsigned)HW) {
                int x = ui * HW + uj;
                int2 e = pb[x];
                if (e.y < rj) {                  // neighbor already added
                    while (e.x != x) {
                        int p = e.x;
                        int2 ep = pb[p];
                        if (ep.x != p) pb[x].x = ep.x;  // halving shortcut
                        x = p; e = ep;
                    }
                    key = (e.y << 10) | x;       // (root pos, root)
                }
            }
        }

        // prefetch next batch's vv (latency hidden behind Phase B)
        int rjN = rb + GB + g;
        int vvN = ordA[(rjN < NPIX) ? rjN : 0];

        // ---- Phase B: register-only resolution ----
        #pragma unroll
        for (int j = 0; j < GB; ++j) {
            if (rb + j >= NPIX) break;           // wave-uniform
            int kk[NN];
            #pragma unroll
            for (int t = 0; t < NN; ++t)
                kk[t] = __builtin_amdgcn_readlane(key, j * NN + t);
            int mn = kk[0];
            #pragma unroll
            for (int t = 1; t < NN; ++t) mn = min(mn, kk[t]);
            int vvj = __builtin_amdgcn_readlane(vv, j * NN);
            int sj = ((rb + j) << 10) | vvj;     // v_j's self key
            int tj = min(mn, sj);                // valid keys < sj always
            int troot = tj & 1023;

            bool slow = false;
            #pragma unroll
            for (int t = 0; t < NN; ++t)
                slow = slow || (kk[t] < 0x100000 && kk[t] != mn);

            if (slow) {                          // >1 distinct component
                bool emit = (g == j) && (key < 0x100000) && (key != mn);
                #pragma unroll
                for (int t = 0; t < NN; ++t)
                    if (t < o && kk[t] == key) emit = false;   // dedupe
                unsigned long long em = __ballot(emit);
                if (emit) {
                    int slot = k + (int)__popcll(em & lmask);
                    pairsI[slot] = (key & 1023) | (vvj << 10);
                    pb[key & 1023].x = troot;    // loser root -> winner
                }
                k += (int)__popcll(em);
                #pragma unroll
                for (int t = 0; t < NN; ++t)     // remap merged roots
                    key = (key == kk[t]) ? tj : key;
            }
            key = (key == sj) ? tj : key;        // in-batch self-root remap
            if (lane == j * NN) pb[vvj].x = troot;  // link v_j
        }
        vv = vvN;
    }
    return k;
}

__global__ void __launch_bounds__(64) uf_land_kernel(const int* __restrict__ POS,
                                                     const int* __restrict__ ORD,
                                                     const float* __restrict__ F,
                                                     float* __restrict__ LAM1,
                                                     float* __restrict__ LAM2) {
    __shared__ int2 pb[NPIX];       // {parent, pos}; pos static
    __shared__ int ordA[NPIX];
    __shared__ float fv[NPIX];      // this task's DTM values
    __shared__ int pairsI[NPIX];    // packed (root | v<<10)
    __shared__ float2 pairs[NPIX];  // (b, d) values
    int lane = threadIdx.x;
    int task = blockIdx.x;
    int feat = task >> 7;
    int dir = (task >> 6) & 1;
    int m = task & 63;
    const int* gpos = POS + task * NPIX;
    const int* gord = ORD + task * NPIX;
    const float* fr = F + feat * NIMG * NPIX + m * NPIX;
    for (int s = lane; s < NPIX; s += 64) {
        pb[s] = make_int2(s, gpos[s]);
        ordA[s] = gord[s];
        fv[s] = fr[s];
    }
    __syncthreads();

    int k;
    if (dir == 0) k = uf_run<4>(pb, ordA, pairsI);
    else          k = uf_run<8>(pb, ordA, pairsI);
    __syncthreads();

    // convert packed pairs to (b, d) float values (dir 1 stores swapped)
    for (int s = lane; s < k; s += 64) {
        int p = pairsI[s];
        float fb = fv[p & 1023], fd = fv[p >> 10];
        pairs[s] = dir ? make_float2(fd, fb) : make_float2(fb, fd);
    }
    __syncthreads();

    // ---- fused landscape: top-3 tents over the k real pairs ----
    if (lane < 32) {
        int t = lane;
        float start = (feat == 0) ? 0.f : 1.f;
        float end   = (feat == 0) ? 7.f : 8.f;
        float tv = start + (end - start) * ((float)t / 31.f);
        float v0 = 0.f, v1 = 0.f, v2 = 0.f;
        for (int p = 0; p < k; ++p) {
            float2 bd = pairs[p];
            float tent = fmaxf(fminf(tv - bd.x, bd.y - tv), 0.f);
            if (tent > v0)      { v2 = v1; v1 = v0; v0 = tent; }
            else if (tent > v1) { v2 = v1; v1 = tent; }
            else if (tent > v2) { v2 = tent; }
        }
        if (feat == 0) {
            float* lam = LAM1 + m * 128 + dir * 64;
            lam[0 * 32 + t] = v0;
            lam[1 * 32 + t] = v1;
        } else {
            float* lam = LAM2 + m * 192 + dir * 96;
            lam[0 * 32 + t] = v0;
            lam[1 * 32 + t] = v1;
            lam[2 * 32 + t] = v2;
        }
    }
}

// ---------------------------------------------------------------------------
// Kernel 6: MLP head. One block (64 threads) per image.
// ---------------------------------------------------------------------------
__global__ void mlp_kernel(const float* __restrict__ LAM1, const float* __restrict__ LAM2,
                           const float* __restrict__ w1, const float* __restrict__ b1,
                           const float* __restrict__ w2, const float* __restrict__ b2,
                           const float* __restrict__ wf, const float* __restrict__ bf,
                           float* __restrict__ out) {
    __shared__ float xc[64];
    int m = blockIdx.x;
    int n = threadIdx.x;
    if (n < 32) {
        float acc = b1[n];
        const float* l = LAM1 + m * 128;
        for (int c = 0; c < 128; ++c) acc += w1[n * 128 + c] * l[c];
        xc[n] = fmaxf(acc, 0.f);
    } else {
        int n2 = n - 32;
        float acc = b2[n2];
        const float* l = LAM2 + m * 192;
        for (int c = 0; c < 192; ++c) acc += w2[n2 * 192 + c] * l[c];
        xc[n] = fmaxf(acc, 0.f);
    }
    __syncthreads();
    if (n < 10) {
        float acc = bf[n];
        for (int c = 0; c < 64; ++c) acc += wf[n * 64 + c] * xc[c];
        out[m * 10 + n] = acc;
    }
}

extern "C" void kernel_launch(void* const* d_in, const int* in_sizes, int n_in,
                              void* d_out, int out_size, void* d_ws, size_t ws_size,
                              hipStream_t stream) {
    const float* x  = (const float*)d_in[0];
    const float* w1 = (const float*)d_in[1];
    const float* b1 = (const float*)d_in[2];
    const float* w2 = (const float*)d_in[3];
    const float* b2 = (const float*)d_in[4];
    const float* wf = (const float*)d_in[5];
    const float* bf = (const float*)d_in[6];
    float* out = (float*)d_out;

    char* ws = (char*)d_ws;
    size_t off = 0;
    unsigned short* SORT = (unsigned short*)(ws + off); off += (size_t)NPIX * NPIX * 2;
    unsigned short* D2S  = (unsigned short*)(ws + off); off += (size_t)NPIX * NPIX * 2;
    float* SUMS = (float*)(ws + off); off += 256;
    float* F    = (float*)(ws + off); off += (size_t)2 * NIMG * NPIX * 4;
    int* POS    = (int*)(ws + off);   off += (size_t)256 * NPIX * 4;
    int* ORD    = (int*)(ws + off);   off += (size_t)256 * NPIX * 4;
    float* LAM1 = (float*)(ws + off); off += (size_t)NIMG * 128 * 4;
    float* LAM2 = (float*)(ws + off); off += (size_t)NIMG * 192 * 4;

    build_consts_kernel<<<NPIX, 256, 0, stream>>>(SORT, D2S);
    row_sum_kernel<<<NIMG, 256, 0, stream>>>(x, SUMS);
    dtm_kernel<<<(NIMG * NPIX) / 4, 256, 0, stream>>>(x, SORT, D2S, SUMS, F);
    rank_kernel<<<256, 256, 0, stream>>>(F, POS, ORD);
    uf_land_kernel<<<256, 64, 0, stream>>>(POS, ORD, F, LAM1, LAM2);
    mlp_kernel<<<NIMG, 64, 0, stream>>>(LAM1, LAM2, w1, b1, w2, b2, wf, bf, out);
}